// Round 2
// baseline (1871.511 us; speedup 1.0000x reference)
//
#include <hip/hip_runtime.h>
#include <float.h>
#include <math.h>

#define NGR 64        // graphs
#define HDIM 128
#define EG 16000      // edges per graph
#define NE (NGR*EG)   // 1,024,000
#define BNEPS 1e-5f

// ---------------- invnorm of pool_w rows (6 layers) ----------------
__global__ void k_invnorm(const float* __restrict__ pw, float* __restrict__ invnorm){
  int i = blockIdx.x;                  // layer
  int t = threadIdx.x;                 // 128 threads
  float v = pw[i*HDIM + t];
  float s = v*v;
  #pragma unroll
  for(int o=32;o>0;o>>=1) s += __shfl_down(s, o, 64);
  __shared__ float red[2];
  if((t & 63)==0) red[t>>6] = s;
  __syncthreads();
  if(t==0) invnorm[i] = 1.0f / sqrtf(red[0]+red[1]);
}

// ---------------- per-graph CSR build (counting sort by dst) + weighted degree ----------------
__global__ __launch_bounds__(512) void k_csr(int n, const int* __restrict__ dstp,
    const float* __restrict__ we,
    int* __restrict__ rp, int* __restrict__ sorted, float* __restrict__ dinv){
  int g = blockIdx.x, t = threadIdx.x;
  __shared__ int   cnt[1024];
  __shared__ int   sc[2][1024];
  __shared__ float degl[1024];
  for(int i=t;i<1024;i+=512){ cnt[i]=0; degl[i]=0.f; }
  __syncthreads();
  int base = g*EG;
  for(int e=base+t; e<base+EG; e+=512){
    float w = we[e];
    if(w != 0.f){
      int ld = dstp[e] - g*n;          // alive edge => in [0,n)
      atomicAdd(&cnt[ld], 1);
      atomicAdd(&degl[ld], w);
    }
  }
  __syncthreads();
  for(int i=t;i<n;i+=512) dinv[g*n+i] = 1.0f / sqrtf(degl[i] + 1.0f);
  // inclusive scan of cnt (Hillis-Steele, ping-pong)
  for(int i=t;i<1024;i+=512) sc[0][i] = cnt[i];
  __syncthreads();
  int buf = 0;
  for(int d=1; d<1024; d<<=1){
    for(int i=t;i<1024;i+=512){
      int v = sc[buf][i];
      if(i>=d) v += sc[buf][i-d];
      sc[buf^1][i] = v;
    }
    __syncthreads();
    buf ^= 1;
  }
  int* rpg = rp + g*(n+1);
  for(int i=t;i<=n;i+=512) rpg[i] = (i==0) ? 0 : sc[buf][i-1];
  for(int i=t;i<1024;i+=512) cnt[i] = (i==0) ? 0 : sc[buf][i-1];  // scatter cursors
  __syncthreads();
  for(int e=base+t; e<base+EG; e+=512){
    float w = we[e];
    if(w != 0.f){
      int ld = dstp[e] - g*n;
      int pos = atomicAdd(&cnt[ld], 1);
      sorted[base+pos] = e;
    }
  }
}

// ---------------- aggregation: agg[d] = sum coef*h[src] + dinv(d)^2 * h[d] ----------------
// L0: h has 64 cols (input features); else 128 cols.
template<int L0>
__global__ __launch_bounds__(256) void k_agg(int n, const int* __restrict__ srcp,
    const float* __restrict__ we,
    const int* __restrict__ rp, const int* __restrict__ sorted,
    const float* __restrict__ dinv, const float* __restrict__ h,
    float* __restrict__ agg){
  int g = blockIdx.x & 63;            // graph-major: all blocks of graph g land on XCD g%8
  int chunk = blockIdx.x >> 6;
  int wid = threadIdx.x >> 6, lane = threadIdx.x & 63;
  const int wpg = (gridDim.x >> 6) * 4;
  const int* rpg = rp + g*(n+1);
  for(int ld = chunk*4 + wid; ld < n; ld += wpg){
    int dg = g*n + ld;
    float dvd = dinv[dg];
    int e0 = rpg[ld], e1 = rpg[ld+1];
    if(L0){
      float acc = 0.f;
      for(int j=e0;j<e1;j++){
        int e = sorted[g*EG + j];
        int s = srcp[e];
        float coef = dinv[s]*dvd*we[e];
        acc += coef * h[(size_t)s*64 + lane];
      }
      acc += dvd*dvd * h[(size_t)dg*64 + lane];
      agg[(size_t)dg*64 + lane] = acc;
    } else {
      float ax=0.f, ay=0.f;
      for(int j=e0;j<e1;j++){
        int e = sorted[g*EG + j];
        int s = srcp[e];
        float coef = dinv[s]*dvd*we[e];
        float2 hv = *(const float2*)(h + (size_t)s*HDIM + 2*lane);
        ax += coef*hv.x; ay += coef*hv.y;
      }
      float sl = dvd*dvd;
      float2 hv = *(const float2*)(h + (size_t)dg*HDIM + 2*lane);
      ax += sl*hv.x; ay += sl*hv.y;
      float2 o; o.x=ax; o.y=ay;
      *(float2*)(agg + (size_t)dg*HDIM + 2*lane) = o;
    }
  }
}

// ---------------- fp32 GEMM (64 rows x 128 cols / block) + bias + BN + ReLU + score ----------------
template<int KIN>
__global__ __launch_bounds__(256) void k_gemm(const float* __restrict__ Ain,
    const float* __restrict__ Wm, const float* __restrict__ bias,
    const float* __restrict__ gamma, const float* __restrict__ beta,
    const float* __restrict__ mean, const float* __restrict__ var,
    const float* __restrict__ pw, const float* __restrict__ invn_p,
    float* __restrict__ hc, float* __restrict__ score){
  __shared__ float As[64*68];    // row-major [row][k], stride 68
  __shared__ float Bs[64*128];   // [k][col]
  int t = threadIdx.x;
  int tx = t & 31, ty = t >> 5;  // thread: rows ty*8..+7, cols tx*4..+3
  int r0 = blockIdx.x * 64;
  float acc[8][4];
  #pragma unroll
  for(int j=0;j<8;j++){
    #pragma unroll
    for(int i=0;i<4;i++) acc[j][i]=0.f;
  }
  for(int k0=0;k0<KIN;k0+=64){
    #pragma unroll
    for(int p=0;p<16;p++){             // stage A 64x64 (coalesced, conflict-free)
      int idx = p*256 + t;
      int kk = idx & 63, rr = idx >> 6;
      As[rr*68 + kk] = Ain[(size_t)(r0+rr)*KIN + k0 + kk];
    }
    #pragma unroll
    for(int p=0;p<32;p++){             // stage B 64x128
      int idx = p*256 + t;
      int kk = idx >> 7, cc = idx & 127;
      Bs[kk*128 + cc] = Wm[(size_t)(k0+kk)*128 + cc];
    }
    __syncthreads();
    #pragma unroll 4
    for(int kk=0;kk<64;kk+=2){
      float4 b0 = *(float4*)&Bs[kk*128 + tx*4];
      float4 b1 = *(float4*)&Bs[(kk+1)*128 + tx*4];
      #pragma unroll
      for(int j=0;j<8;j++){
        float2 a = *(float2*)&As[(ty*8+j)*68 + kk];
        acc[j][0] += a.x*b0.x; acc[j][1] += a.x*b0.y;
        acc[j][2] += a.x*b0.z; acc[j][3] += a.x*b0.w;
        acc[j][0] += a.y*b1.x; acc[j][1] += a.y*b1.y;
        acc[j][2] += a.y*b1.z; acc[j][3] += a.y*b1.w;
      }
    }
    __syncthreads();
  }
  // epilogue: bias + BN + ReLU, write hc, score = tanh(dot(hc,pw)*invnorm)
  float invn = invn_p[0];
  float bi[4], scv[4], bt[4], mn[4], pwv[4];
  #pragma unroll
  for(int i=0;i<4;i++){
    int c = tx*4+i;
    bi[i]  = bias[c];
    scv[i] = gamma[c] * (1.0f/sqrtf(var[c] + BNEPS));
    bt[i]  = beta[c];
    mn[i]  = mean[c];
    pwv[i] = pw[c];
  }
  #pragma unroll
  for(int j=0;j<8;j++){
    int row = r0 + ty*8 + j;
    float v0 = fmaxf((acc[j][0]+bi[0]-mn[0])*scv[0]+bt[0], 0.f);
    float v1 = fmaxf((acc[j][1]+bi[1]-mn[1])*scv[1]+bt[1], 0.f);
    float v2 = fmaxf((acc[j][2]+bi[2]-mn[2])*scv[2]+bt[2], 0.f);
    float v3 = fmaxf((acc[j][3]+bi[3]-mn[3])*scv[3]+bt[3], 0.f);
    float4 o; o.x=v0; o.y=v1; o.z=v2; o.w=v3;
    *(float4*)(hc + (size_t)row*HDIM + tx*4) = o;
    float p = v0*pwv[0]+v1*pwv[1]+v2*pwv[2]+v3*pwv[3];
    #pragma unroll
    for(int m=16;m>=1;m>>=1) p += __shfl_xor(p, m, 64);
    if(tx==0) score[row] = tanhf(p * invn);
  }
}

// ---------------- per-graph top-k: bitonic sort (score desc, idx asc) ----------------
__global__ __launch_bounds__(512) void k_topk(int n, int k, int P,
    const float* __restrict__ score, int* __restrict__ perm, float* __restrict__ vals,
    int* __restrict__ inv){
  int g = blockIdx.x, t = threadIdx.x;
  __shared__ float s[1024];
  __shared__ int  id[1024];
  for(int i=t;i<P;i+=512){
    s[i]  = (i<n) ? score[g*n+i] : -FLT_MAX;
    id[i] = i;
  }
  __syncthreads();
  for(int k2=2;k2<=P;k2<<=1){
    for(int j=k2>>1;j>0;j>>=1){
      for(int i=t;i<P;i+=512){
        int ixj = i ^ j;
        if(ixj > i){
          bool desc = ((i & k2) == 0);
          float si = s[i], sx = s[ixj];
          int ii = id[i], ix = id[ixj];
          bool pre = (si > sx) || (si == sx && ii < ix);  // i precedes in desc order
          if(desc ? !pre : pre){ s[i]=sx; s[ixj]=si; id[i]=ix; id[ixj]=ii; }
        }
      }
      __syncthreads();
    }
  }
  for(int i=t;i<n;i+=512){
    int idx = id[i];
    if(i<k){ perm[g*k+i]=idx; vals[g*k+i]=s[i]; inv[g*n+idx]=g*k+i; }
    else inv[g*n+idx] = -1;
  }
}

// ---------------- edge remap ----------------
__global__ void k_remap(const int* __restrict__ inv, const int* __restrict__ si,
    const int* __restrict__ di, const float* __restrict__ wf,
    int* __restrict__ so, int* __restrict__ dou, float* __restrict__ wo){
  int e = blockIdx.x*256 + threadIdx.x;
  if(e >= NE) return;
  int s = si[e], d = di[e];
  float w = wf[e];
  int is = inv[s], idd = inv[d];
  bool ok = (w != 0.f) && (is >= 0) && (idd >= 0);
  so[e]  = ok ? is  : 0;
  dou[e] = ok ? idd : 0;
  wo[e]  = ok ? w   : 0.f;
}

// ---------------- gather h_next = hc[perm]*vals + mean/max pooling into flats ----------------
__global__ __launch_bounds__(256) void k_gatherpool(int n, int k,
    const float* __restrict__ hc, const int* __restrict__ perm, const float* __restrict__ vals,
    float* __restrict__ hnext, float* __restrict__ flats){
  int g = blockIdx.x;
  int f = threadIdx.x & 127, half = threadIdx.x >> 7;
  float sum = 0.f, mx = -FLT_MAX;
  for(int j=half; j<k; j+=2){
    int idx = perm[g*k+j];
    float v = vals[g*k+j];
    float val = hc[(size_t)(g*n+idx)*HDIM + f] * v;
    hnext[(size_t)(g*k+j)*HDIM + f] = val;
    sum += val; mx = fmaxf(mx, val);
  }
  __shared__ float ssum[2][128], smax[2][128];
  ssum[half][f]=sum; smax[half][f]=mx;
  __syncthreads();
  if(half==0){
    float s = ssum[0][f]+ssum[1][f];
    float m = fmaxf(smax[0][f], smax[1][f]);
    flats[g*256+f]       += s / (float)k;
    flats[g*256+128+f]   += m;
  }
}

// ---------------- MLP head ----------------
__global__ __launch_bounds__(512) void k_head(const float* __restrict__ flats,
    const float* __restrict__ d1w, const float* __restrict__ d1b,
    const float* __restrict__ d2w, const float* __restrict__ d2b, float* __restrict__ out){
  int g = blockIdx.x, j = threadIdx.x;
  __shared__ float fl[256];
  __shared__ float hd[512];
  for(int i=j;i<256;i+=512) fl[i] = flats[g*256+i];
  __syncthreads();
  float acc = d1b[j];
  for(int i=0;i<256;i++) acc += fl[i]*d1w[i*512+j];
  hd[j] = fmaxf(acc, 0.f);
  __syncthreads();
  if(j < 10){
    float a = d2b[j];
    for(int i=0;i<512;i++) a += hd[i]*d2w[i*10+j];
    out[g*10+j] = a;
  }
}

extern "C" void kernel_launch(void* const* d_in, const int* in_sizes, int n_in,
                              void* d_out, int out_size, void* d_ws, size_t ws_size,
                              hipStream_t stream) {
  const float* x    = (const float*)d_in[0];
  const int* ei     = (const int*)d_in[1];
  const float* ew   = (const float*)d_in[3];
  const float* conv1w = (const float*)d_in[4];
  const float* convw  = (const float*)d_in[5];
  const float* convb  = (const float*)d_in[6];
  const float* bng    = (const float*)d_in[7];
  const float* bnb    = (const float*)d_in[8];
  const float* bnm    = (const float*)d_in[9];
  const float* bnv    = (const float*)d_in[10];
  const float* poolw  = (const float*)d_in[11];
  const float* d1w    = (const float*)d_in[12];
  const float* d1b    = (const float*)d_in[13];
  const float* d2w    = (const float*)d_in[14];
  const float* d2b    = (const float*)d_in[15];
  float* out = (float*)d_out;

  char* w = (char*)d_ws;
  float* hc    = (float*)w; w += (size_t)64000*128*4;   // agg(1..5)/gemm in-place + layer0 gemm out
  float* agg0  = (float*)w; w += (size_t)64000*64*4;    // layer0 aggregation (64 cols)
  float* hbuf  = (float*)w; w += (size_t)51200*128*4;   // pooled features (layer input 1..5)
  int*   csrc  = (int*)w;   w += (size_t)NE*4;
  int*   cdst  = (int*)w;   w += (size_t)NE*4;
  float* cwe   = (float*)w; w += (size_t)NE*4;
  int*   sorted= (int*)w;   w += (size_t)NE*4;
  int*   rp    = (int*)w;   w += (size_t)64*1008*4;
  float* dinv  = (float*)w; w += (size_t)64000*4;
  float* score = (float*)w; w += (size_t)64000*4;
  int*   perm  = (int*)w;   w += (size_t)51200*4;
  float* vals  = (float*)w; w += (size_t)51200*4;
  int*   inv   = (int*)w;   w += (size_t)64000*4;
  float* flats = (float*)w; w += (size_t)64*256*4;
  float* invno = (float*)w; w += 64;

  hipMemsetAsync(flats, 0, 64*256*4, stream);
  k_invnorm<<<6,128,0,stream>>>(poolw, invno);

  const int ns[6]={1000,800,640,512,410,328};
  const int ks[6]={800,640,512,410,328,263};

  // ---- layer 0 (input = x, 64 cols) ----
  k_csr<<<64,512,0,stream>>>(1000, ei+NE, ew, rp, sorted, dinv);
  k_agg<1><<<64*16,256,0,stream>>>(1000, ei, ew, rp, sorted, dinv, x, agg0);
  k_gemm<64><<<1000,256,0,stream>>>(agg0, conv1w, convb, bng, bnb, bnm, bnv, poolw, invno, hc, score);
  k_topk<<<64,512,0,stream>>>(1000, 800, 1024, score, perm, vals, inv);
  k_remap<<<(NE+255)/256,256,0,stream>>>(inv, ei, ei+NE, ew, csrc, cdst, cwe);
  k_gatherpool<<<64,256,0,stream>>>(1000, 800, hc, perm, vals, hbuf, flats);

  // ---- layers 1..5 ----
  for(int i=1;i<6;i++){
    int n = ns[i], k = ks[i];
    k_csr<<<64,512,0,stream>>>(n, cdst, cwe, rp, sorted, dinv);
    k_agg<0><<<64*16,256,0,stream>>>(n, csrc, cwe, rp, sorted, dinv, hbuf, hc);
    k_gemm<128><<<n,256,0,stream>>>(hc, convw+(size_t)(i-1)*128*128, convb+i*128, bng+i*128,
                                    bnb+i*128, bnm+i*128, bnv+i*128, poolw+i*128, invno+i, hc, score);
    int P = (n > 512) ? 1024 : 512;
    k_topk<<<64,512,0,stream>>>(n, k, P, score, perm, vals, inv);
    if(i<5) k_remap<<<(NE+255)/256,256,0,stream>>>(inv, csrc, cdst, cwe, csrc, cdst, cwe);
    k_gatherpool<<<64,256,0,stream>>>(n, k, hc, perm, vals, hbuf, flats);
  }

  k_head<<<64,512,0,stream>>>(flats, d1w, d1b, d2w, d2b, out);
}

// Round 3
// 1230.392 us; speedup vs baseline: 1.5211x; 1.5211x over previous
//
#include <hip/hip_runtime.h>
#include <float.h>
#include <math.h>

#define NGR 64        // graphs
#define HDIM 128
#define EG 16000      // edges per graph
#define NE (NGR*EG)   // 1,024,000
#define BNEPS 1e-5f

// monotone float<->uint order mapping (no NaNs in this workload)
__device__ __forceinline__ unsigned ford(float x){
  unsigned u = __float_as_uint(x);
  return (u & 0x80000000u) ? ~u : (u | 0x80000000u);
}
__device__ __forceinline__ float funord(unsigned u){
  return (u & 0x80000000u) ? __uint_as_float(u ^ 0x80000000u) : __uint_as_float(~u);
}
#define FORD_NEGMAX 0x00800000u   // ford(-FLT_MAX)

// ---------------- invnorm of pool_w rows (6 layers) ----------------
__global__ void k_invnorm(const float* __restrict__ pw, float* __restrict__ invnorm){
  int i = blockIdx.x;                  // layer
  int t = threadIdx.x;                 // 128 threads
  float v = pw[i*HDIM + t];
  float s = v*v;
  #pragma unroll
  for(int o=32;o>0;o>>=1) s += __shfl_down(s, o, 64);
  __shared__ float red[2];
  if((t & 63)==0) red[t>>6] = s;
  __syncthreads();
  if(t==0) invnorm[i] = 1.0f / sqrtf(red[0]+red[1]);
}

// ---------------- init pooling staging buffers ----------------
__global__ void k_poolinit(float* __restrict__ sumstage, unsigned* __restrict__ maxstage){
  int i = blockIdx.x*256 + threadIdx.x;   // 64*128 = 8192 elements
  if(i < NGR*HDIM){ sumstage[i] = 0.f; maxstage[i] = FORD_NEGMAX; }
}

// ---------------- per-graph CSR build (counting sort by dst) + weighted degree ----------------
__global__ __launch_bounds__(512) void k_csr(int n, const int* __restrict__ dstp,
    const float* __restrict__ we,
    int* __restrict__ rp, int* __restrict__ sorted, float* __restrict__ dinv){
  int g = blockIdx.x, t = threadIdx.x;
  __shared__ int   cnt[1024];
  __shared__ int   sc[2][1024];
  __shared__ float degl[1024];
  for(int i=t;i<1024;i+=512){ cnt[i]=0; degl[i]=0.f; }
  __syncthreads();
  int base = g*EG;
  for(int e=base+t; e<base+EG; e+=512){
    float w = we[e];
    if(w != 0.f){
      int ld = dstp[e] - g*n;          // alive edge => in [0,n)
      atomicAdd(&cnt[ld], 1);
      atomicAdd(&degl[ld], w);
    }
  }
  __syncthreads();
  for(int i=t;i<n;i+=512) dinv[g*n+i] = 1.0f / sqrtf(degl[i] + 1.0f);
  // inclusive scan of cnt (Hillis-Steele, ping-pong)
  for(int i=t;i<1024;i+=512) sc[0][i] = cnt[i];
  __syncthreads();
  int buf = 0;
  for(int d=1; d<1024; d<<=1){
    for(int i=t;i<1024;i+=512){
      int v = sc[buf][i];
      if(i>=d) v += sc[buf][i-d];
      sc[buf^1][i] = v;
    }
    __syncthreads();
    buf ^= 1;
  }
  int* rpg = rp + g*(n+1);
  for(int i=t;i<=n;i+=512) rpg[i] = (i==0) ? 0 : sc[buf][i-1];
  for(int i=t;i<1024;i+=512) cnt[i] = (i==0) ? 0 : sc[buf][i-1];  // scatter cursors
  __syncthreads();
  for(int e=base+t; e<base+EG; e+=512){
    float w = we[e];
    if(w != 0.f){
      int ld = dstp[e] - g*n;
      int pos = atomicAdd(&cnt[ld], 1);
      sorted[base+pos] = e;
    }
  }
}

// ---------------- aggregation: agg[d] = sum coef*h[src] + dinv(d)^2 * h[d] ----------------
// L0: h has 64 cols (input features); else 128 cols.
template<int L0>
__global__ __launch_bounds__(256) void k_agg(int n, const int* __restrict__ srcp,
    const float* __restrict__ we,
    const int* __restrict__ rp, const int* __restrict__ sorted,
    const float* __restrict__ dinv, const float* __restrict__ h,
    float* __restrict__ agg){
  int g = blockIdx.x & 63;            // graph-major: all blocks of graph g land on XCD g%8
  int chunk = blockIdx.x >> 6;
  int wid = threadIdx.x >> 6, lane = threadIdx.x & 63;
  const int wpg = (gridDim.x >> 6) * 4;
  const int* rpg = rp + g*(n+1);
  for(int ld = chunk*4 + wid; ld < n; ld += wpg){
    int dg = g*n + ld;
    float dvd = dinv[dg];
    int e0 = rpg[ld], e1 = rpg[ld+1];
    if(L0){
      float acc = 0.f;
      for(int j=e0;j<e1;j++){
        int e = sorted[g*EG + j];
        int s = srcp[e];
        float coef = dinv[s]*dvd*we[e];
        acc += coef * h[(size_t)s*64 + lane];
      }
      acc += dvd*dvd * h[(size_t)dg*64 + lane];
      agg[(size_t)dg*64 + lane] = acc;
    } else {
      float ax=0.f, ay=0.f;
      for(int j=e0;j<e1;j++){
        int e = sorted[g*EG + j];
        int s = srcp[e];
        float coef = dinv[s]*dvd*we[e];
        float2 hv = *(const float2*)(h + (size_t)s*HDIM + 2*lane);
        ax += coef*hv.x; ay += coef*hv.y;
      }
      float sl = dvd*dvd;
      float2 hv = *(const float2*)(h + (size_t)dg*HDIM + 2*lane);
      ax += sl*hv.x; ay += sl*hv.y;
      float2 o; o.x=ax; o.y=ay;
      *(float2*)(agg + (size_t)dg*HDIM + 2*lane) = o;
    }
  }
}

// ---------------- fp32 GEMM (64 rows x 128 cols / block) + bias + BN + ReLU + score ----------------
template<int KIN>
__global__ __launch_bounds__(256) void k_gemm(const float* __restrict__ Ain,
    const float* __restrict__ Wm, const float* __restrict__ bias,
    const float* __restrict__ gamma, const float* __restrict__ beta,
    const float* __restrict__ mean, const float* __restrict__ var,
    const float* __restrict__ pw, const float* __restrict__ invn_p,
    float* __restrict__ hc, float* __restrict__ score){
  __shared__ float As[64*68];    // row-major [row][k], stride 68
  __shared__ float Bs[64*128];   // [k][col]
  int t = threadIdx.x;
  int tx = t & 31, ty = t >> 5;  // thread: rows ty*8..+7, cols tx*4..+3
  int r0 = blockIdx.x * 64;
  float acc[8][4];
  #pragma unroll
  for(int j=0;j<8;j++){
    #pragma unroll
    for(int i=0;i<4;i++) acc[j][i]=0.f;
  }
  for(int k0=0;k0<KIN;k0+=64){
    #pragma unroll
    for(int p=0;p<16;p++){             // stage A 64x64 (coalesced, conflict-free)
      int idx = p*256 + t;
      int kk = idx & 63, rr = idx >> 6;
      As[rr*68 + kk] = Ain[(size_t)(r0+rr)*KIN + k0 + kk];
    }
    #pragma unroll
    for(int p=0;p<32;p++){             // stage B 64x128
      int idx = p*256 + t;
      int kk = idx >> 7, cc = idx & 127;
      Bs[kk*128 + cc] = Wm[(size_t)(k0+kk)*128 + cc];
    }
    __syncthreads();
    #pragma unroll 4
    for(int kk=0;kk<64;kk+=2){
      float4 b0 = *(float4*)&Bs[kk*128 + tx*4];
      float4 b1 = *(float4*)&Bs[(kk+1)*128 + tx*4];
      #pragma unroll
      for(int j=0;j<8;j++){
        float2 a = *(float2*)&As[(ty*8+j)*68 + kk];
        acc[j][0] += a.x*b0.x; acc[j][1] += a.x*b0.y;
        acc[j][2] += a.x*b0.z; acc[j][3] += a.x*b0.w;
        acc[j][0] += a.y*b1.x; acc[j][1] += a.y*b1.y;
        acc[j][2] += a.y*b1.z; acc[j][3] += a.y*b1.w;
      }
    }
    __syncthreads();
  }
  // epilogue: bias + BN + ReLU, write hc, score = tanh(dot(hc,pw)*invnorm)
  float invn = invn_p[0];
  float bi[4], scv[4], bt[4], mn[4], pwv[4];
  #pragma unroll
  for(int i=0;i<4;i++){
    int c = tx*4+i;
    bi[i]  = bias[c];
    scv[i] = gamma[c] * (1.0f/sqrtf(var[c] + BNEPS));
    bt[i]  = beta[c];
    mn[i]  = mean[c];
    pwv[i] = pw[c];
  }
  #pragma unroll
  for(int j=0;j<8;j++){
    int row = r0 + ty*8 + j;
    float v0 = fmaxf((acc[j][0]+bi[0]-mn[0])*scv[0]+bt[0], 0.f);
    float v1 = fmaxf((acc[j][1]+bi[1]-mn[1])*scv[1]+bt[1], 0.f);
    float v2 = fmaxf((acc[j][2]+bi[2]-mn[2])*scv[2]+bt[2], 0.f);
    float v3 = fmaxf((acc[j][3]+bi[3]-mn[3])*scv[3]+bt[3], 0.f);
    float4 o; o.x=v0; o.y=v1; o.z=v2; o.w=v3;
    *(float4*)(hc + (size_t)row*HDIM + tx*4) = o;
    float p = v0*pwv[0]+v1*pwv[1]+v2*pwv[2]+v3*pwv[3];
    #pragma unroll
    for(int m=16;m>=1;m>>=1) p += __shfl_xor(p, m, 64);
    if(tx==0) score[row] = tanhf(p * invn);
  }
}

// ---------------- per-graph top-k: bitonic sort (score desc, idx asc) ----------------
__global__ __launch_bounds__(512) void k_topk(int n, int k, int P,
    const float* __restrict__ score, int* __restrict__ perm, float* __restrict__ vals,
    int* __restrict__ inv){
  int g = blockIdx.x, t = threadIdx.x;
  __shared__ float s[1024];
  __shared__ int  id[1024];
  for(int i=t;i<P;i+=512){
    s[i]  = (i<n) ? score[g*n+i] : -FLT_MAX;
    id[i] = i;
  }
  __syncthreads();
  for(int k2=2;k2<=P;k2<<=1){
    for(int j=k2>>1;j>0;j>>=1){
      for(int i=t;i<P;i+=512){
        int ixj = i ^ j;
        if(ixj > i){
          bool desc = ((i & k2) == 0);
          float si = s[i], sx = s[ixj];
          int ii = id[i], ix = id[ixj];
          bool pre = (si > sx) || (si == sx && ii < ix);  // i precedes in desc order
          if(desc ? !pre : pre){ s[i]=sx; s[ixj]=si; id[i]=ix; id[ixj]=ii; }
        }
      }
      __syncthreads();
    }
  }
  for(int i=t;i<n;i+=512){
    int idx = id[i];
    if(i<k){ perm[g*k+i]=idx; vals[g*k+i]=s[i]; inv[g*n+idx]=g*k+i; }
    else inv[g*n+idx] = -1;
  }
}

// ---------------- edge remap ----------------
__global__ void k_remap(const int* __restrict__ inv, const int* __restrict__ si,
    const int* __restrict__ di, const float* __restrict__ wf,
    int* __restrict__ so, int* __restrict__ dou, float* __restrict__ wo){
  int e = blockIdx.x*256 + threadIdx.x;
  if(e >= NE) return;
  int s = si[e], d = di[e];
  float w = wf[e];
  int is = inv[s], idd = inv[d];
  bool ok = (w != 0.f) && (is >= 0) && (idd >= 0);
  so[e]  = ok ? is  : 0;
  dou[e] = ok ? idd : 0;
  wo[e]  = ok ? w   : 0.f;
}

// ---------------- gather h_next = hc[perm]*vals, partial mean/max pooling ----------------
// grid = 64 graphs * NB blocks (graph-major for XCD locality), 256 threads = 4 waves,
// one wave per row per iteration, float2 per lane.
#define POOL_NB 32
__global__ __launch_bounds__(256) void k_gatherpool(int n, int k,
    const float* __restrict__ hc, const int* __restrict__ perm, const float* __restrict__ vals,
    float* __restrict__ hnext, float* __restrict__ sumstage, unsigned* __restrict__ maxstage){
  int g = blockIdx.x & 63;
  int chunk = blockIdx.x >> 6;
  int wid = threadIdx.x >> 6, lane = threadIdx.x & 63;
  float2 psum; psum.x = 0.f; psum.y = 0.f;
  float2 pmax; pmax.x = -FLT_MAX; pmax.y = -FLT_MAX;
  for(int j = chunk*4 + wid; j < k; j += POOL_NB*4){
    int idx = perm[g*k+j];
    float v = vals[g*k+j];
    float2 hv = *(const float2*)(hc + (size_t)(g*n+idx)*HDIM + 2*lane);
    float2 o; o.x = hv.x*v; o.y = hv.y*v;
    *(float2*)(hnext + (size_t)(g*k+j)*HDIM + 2*lane) = o;
    psum.x += o.x; psum.y += o.y;
    pmax.x = fmaxf(pmax.x, o.x); pmax.y = fmaxf(pmax.y, o.y);
  }
  __shared__ float ss[4][128];
  __shared__ float sm[4][128];
  *(float2*)&ss[wid][2*lane] = psum;
  *(float2*)&sm[wid][2*lane] = pmax;
  __syncthreads();
  int t = threadIdx.x;
  if(t < 128){
    float s = (ss[0][t]+ss[1][t]) + (ss[2][t]+ss[3][t]);
    float m = fmaxf(fmaxf(sm[0][t], sm[1][t]), fmaxf(sm[2][t], sm[3][t]));
    atomicAdd(&sumstage[g*HDIM + t], s);
    atomicMax(&maxstage[g*HDIM + t], ford(m));
  }
}

// ---------------- fold pooling staging into flats, reset staging ----------------
__global__ void k_poolmerge(int k, float* __restrict__ flats,
    float* __restrict__ sumstage, unsigned* __restrict__ maxstage){
  int g = blockIdx.x, t = threadIdx.x;    // 64 blocks x 128 threads
  float s = sumstage[g*HDIM + t];
  float m = funord(maxstage[g*HDIM + t]);
  flats[g*256 + t]       += s / (float)k;
  flats[g*256 + 128 + t] += m;
  sumstage[g*HDIM + t] = 0.f;
  maxstage[g*HDIM + t] = FORD_NEGMAX;
}

// ---------------- MLP head ----------------
__global__ __launch_bounds__(512) void k_head(const float* __restrict__ flats,
    const float* __restrict__ d1w, const float* __restrict__ d1b,
    const float* __restrict__ d2w, const float* __restrict__ d2b, float* __restrict__ out){
  int g = blockIdx.x, j = threadIdx.x;
  __shared__ float fl[256];
  __shared__ float hd[512];
  for(int i=j;i<256;i+=512) fl[i] = flats[g*256+i];
  __syncthreads();
  float acc = d1b[j];
  for(int i=0;i<256;i++) acc += fl[i]*d1w[i*512+j];
  hd[j] = fmaxf(acc, 0.f);
  __syncthreads();
  if(j < 10){
    float a = d2b[j];
    for(int i=0;i<512;i++) a += hd[i]*d2w[i*10+j];
    out[g*10+j] = a;
  }
}

extern "C" void kernel_launch(void* const* d_in, const int* in_sizes, int n_in,
                              void* d_out, int out_size, void* d_ws, size_t ws_size,
                              hipStream_t stream) {
  const float* x    = (const float*)d_in[0];
  const int* ei     = (const int*)d_in[1];
  const float* ew   = (const float*)d_in[3];
  const float* conv1w = (const float*)d_in[4];
  const float* convw  = (const float*)d_in[5];
  const float* convb  = (const float*)d_in[6];
  const float* bng    = (const float*)d_in[7];
  const float* bnb    = (const float*)d_in[8];
  const float* bnm    = (const float*)d_in[9];
  const float* bnv    = (const float*)d_in[10];
  const float* poolw  = (const float*)d_in[11];
  const float* d1w    = (const float*)d_in[12];
  const float* d1b    = (const float*)d_in[13];
  const float* d2w    = (const float*)d_in[14];
  const float* d2b    = (const float*)d_in[15];
  float* out = (float*)d_out;

  char* w = (char*)d_ws;
  float* hc    = (float*)w; w += (size_t)64000*128*4;   // agg(1..5)/gemm in-place + layer0 gemm out
  float* agg0  = (float*)w; w += (size_t)64000*64*4;    // layer0 aggregation (64 cols)
  float* hbuf  = (float*)w; w += (size_t)51200*128*4;   // pooled features (layer input 1..5)
  int*   csrc  = (int*)w;   w += (size_t)NE*4;
  int*   cdst  = (int*)w;   w += (size_t)NE*4;
  float* cwe   = (float*)w; w += (size_t)NE*4;
  int*   sorted= (int*)w;   w += (size_t)NE*4;
  int*   rp    = (int*)w;   w += (size_t)64*1008*4;
  float* dinv  = (float*)w; w += (size_t)64000*4;
  float* score = (float*)w; w += (size_t)64000*4;
  int*   perm  = (int*)w;   w += (size_t)51200*4;
  float* vals  = (float*)w; w += (size_t)51200*4;
  int*   inv   = (int*)w;   w += (size_t)64000*4;
  float* flats = (float*)w; w += (size_t)64*256*4;
  float* invno = (float*)w; w += 64;
  float* sumstage = (float*)w; w += (size_t)NGR*HDIM*4;
  unsigned* maxstage = (unsigned*)w; w += (size_t)NGR*HDIM*4;

  hipMemsetAsync(flats, 0, 64*256*4, stream);
  k_invnorm<<<6,128,0,stream>>>(poolw, invno);
  k_poolinit<<<(NGR*HDIM+255)/256,256,0,stream>>>(sumstage, maxstage);

  const int ns[6]={1000,800,640,512,410,328};
  const int ks[6]={800,640,512,410,328,263};

  // ---- layer 0 (input = x, 64 cols) ----
  k_csr<<<64,512,0,stream>>>(1000, ei+NE, ew, rp, sorted, dinv);
  k_agg<1><<<64*16,256,0,stream>>>(1000, ei, ew, rp, sorted, dinv, x, agg0);
  k_gemm<64><<<1000,256,0,stream>>>(agg0, conv1w, convb, bng, bnb, bnm, bnv, poolw, invno, hc, score);
  k_topk<<<64,512,0,stream>>>(1000, 800, 1024, score, perm, vals, inv);
  k_remap<<<(NE+255)/256,256,0,stream>>>(inv, ei, ei+NE, ew, csrc, cdst, cwe);
  k_gatherpool<<<64*POOL_NB,256,0,stream>>>(1000, 800, hc, perm, vals, hbuf, sumstage, maxstage);
  k_poolmerge<<<64,128,0,stream>>>(800, flats, sumstage, maxstage);

  // ---- layers 1..5 ----
  for(int i=1;i<6;i++){
    int n = ns[i], k = ks[i];
    k_csr<<<64,512,0,stream>>>(n, cdst, cwe, rp, sorted, dinv);
    k_agg<0><<<64*16,256,0,stream>>>(n, csrc, cwe, rp, sorted, dinv, hbuf, hc);
    k_gemm<128><<<n,256,0,stream>>>(hc, convw+(size_t)(i-1)*128*128, convb+i*128, bng+i*128,
                                    bnb+i*128, bnm+i*128, bnv+i*128, poolw+i*128, invno+i, hc, score);
    int P = (n > 512) ? 1024 : 512;
    k_topk<<<64,512,0,stream>>>(n, k, P, score, perm, vals, inv);
    if(i<5) k_remap<<<(NE+255)/256,256,0,stream>>>(inv, csrc, cdst, cwe, csrc, cdst, cwe);
    k_gatherpool<<<64*POOL_NB,256,0,stream>>>(n, k, hc, perm, vals, hbuf, sumstage, maxstage);
    k_poolmerge<<<64,128,0,stream>>>(k, flats, sumstage, maxstage);
  }

  k_head<<<64,512,0,stream>>>(flats, d1w, d1b, d2w, d2b, out);
}

// Round 4
// 869.005 us; speedup vs baseline: 2.1536x; 1.4159x over previous
//
#include <hip/hip_runtime.h>
#include <float.h>
#include <math.h>

#define NGR 64        // graphs
#define HDIM 128
#define EG 16000      // edges per graph
#define NE (NGR*EG)   // 1,024,000
#define BNEPS 1e-5f

// monotone float<->uint order mapping (no NaNs in this workload)
__device__ __forceinline__ unsigned ford(float x){
  unsigned u = __float_as_uint(x);
  return (u & 0x80000000u) ? ~u : (u | 0x80000000u);
}
__device__ __forceinline__ float funord(unsigned u){
  return (u & 0x80000000u) ? __uint_as_float(u ^ 0x80000000u) : __uint_as_float(~u);
}
#define FORD_NEGMAX 0x00800000u   // ford(-FLT_MAX)

// ---------------- invnorm of pool_w rows (6 layers) ----------------
__global__ void k_invnorm(const float* __restrict__ pw, float* __restrict__ invnorm){
  int i = blockIdx.x;                  // layer
  int t = threadIdx.x;                 // 128 threads
  float v = pw[i*HDIM + t];
  float s = v*v;
  #pragma unroll
  for(int o=32;o>0;o>>=1) s += __shfl_down(s, o, 64);
  __shared__ float red[2];
  if((t & 63)==0) red[t>>6] = s;
  __syncthreads();
  if(t==0) invnorm[i] = 1.0f / sqrtf(red[0]+red[1]);
}

// ---------------- init pooling staging buffers ----------------
__global__ void k_poolinit(float* __restrict__ sumstage, unsigned* __restrict__ maxstage){
  int i = blockIdx.x*256 + threadIdx.x;   // 64*128 = 8192 elements
  if(i < NGR*HDIM){ sumstage[i] = 0.f; maxstage[i] = FORD_NEGMAX; }
}

// ---------------- per-graph CSR build (counting sort by dst) + weighted degree ----------------
// Emits per-edge packed records ec[pos] = (coef<<32 | src_global) in dst-sorted order,
// where coef = dinv[src]*dinv[dst]*w  (dinv held in LDS from the degree pass).
__global__ __launch_bounds__(512) void k_csr(int n, const int* __restrict__ srcp,
    const int* __restrict__ dstp, const float* __restrict__ we,
    int* __restrict__ rp, long long* __restrict__ ec, float* __restrict__ dinv){
  int g = blockIdx.x, t = threadIdx.x;
  __shared__ int   cnt[1024];
  __shared__ int   sc[2][1024];
  __shared__ float degl[1024];          // degree, then converted in-place to dinv
  for(int i=t;i<1024;i+=512){ cnt[i]=0; degl[i]=0.f; }
  __syncthreads();
  int base = g*EG;
  for(int e=base+t; e<base+EG; e+=512){
    float w = we[e];
    if(w != 0.f){
      int ld = dstp[e] - g*n;          // alive edge => in [0,n)
      atomicAdd(&cnt[ld], 1);
      atomicAdd(&degl[ld], w);
    }
  }
  __syncthreads();
  for(int i=t;i<n;i+=512){
    float dv = 1.0f / sqrtf(degl[i] + 1.0f);
    degl[i] = dv;                       // in-place: degl now holds dinv (local)
    dinv[g*n+i] = dv;
  }
  // inclusive scan of cnt (Hillis-Steele, ping-pong)
  for(int i=t;i<1024;i+=512) sc[0][i] = cnt[i];
  __syncthreads();
  int buf = 0;
  for(int d=1; d<1024; d<<=1){
    for(int i=t;i<1024;i+=512){
      int v = sc[buf][i];
      if(i>=d) v += sc[buf][i-d];
      sc[buf^1][i] = v;
    }
    __syncthreads();
    buf ^= 1;
  }
  int* rpg = rp + g*(n+1);
  for(int i=t;i<=n;i+=512) rpg[i] = (i==0) ? 0 : sc[buf][i-1];
  for(int i=t;i<1024;i+=512) cnt[i] = (i==0) ? 0 : sc[buf][i-1];  // scatter cursors
  __syncthreads();
  for(int e=base+t; e<base+EG; e+=512){
    float w = we[e];
    if(w != 0.f){
      int s  = srcp[e];
      int ls = s - g*n;
      int ld = dstp[e] - g*n;
      float coef = degl[ls] * degl[ld] * w;
      int pos = atomicAdd(&cnt[ld], 1);
      long long pk = (((long long)__float_as_int(coef)) << 32) | (unsigned int)s;
      ec[base+pos] = pk;
    }
  }
}

// ---------------- aggregation: agg[d] = sum coef*h[src] + dinv(d)^2 * h[d] ----------------
// One wave per dst node. Edge records batch-loaded 64 at a time (8B/lane), broadcast
// via shfl; h-row gathers unrolled x8 so loads pipeline. Padding lanes decode to
// (src=0, coef=0) -> harmless.
template<int L0>
__global__ __launch_bounds__(256) void k_agg(int n, const int* __restrict__ rp,
    const long long* __restrict__ ecpk, const float* __restrict__ dinv,
    const float* __restrict__ h, float* __restrict__ agg){
  int g = blockIdx.x & 63;            // graph-major: all blocks of graph g land on XCD g%8
  int chunk = blockIdx.x >> 6;
  int wid = threadIdx.x >> 6, lane = threadIdx.x & 63;
  const int wpg = (gridDim.x >> 6) * 4;
  const int* rpg = rp + g*(n+1);
  const long long* ec = ecpk + (size_t)g*EG;
  for(int ld = chunk*4 + wid; ld < n; ld += wpg){
    int dg = g*n + ld;
    int e0 = rpg[ld], e1 = rpg[ld+1];
    if(L0){
      float acc = 0.f;
      for(int b=e0;b<e1;b+=64){
        int mm = e1-b; if(mm>64) mm=64;
        long long pk = (lane<mm) ? ec[b+lane] : 0;
        int mr = (mm+7) & ~7;
        for(int jj=0;jj<mr;jj+=8){
          #pragma unroll
          for(int u=0;u<8;u++){
            long long p = __shfl(pk, jj+u, 64);
            int s = (int)(p & 0xffffffffLL);
            float c = __int_as_float((int)(p>>32));
            acc += c * h[(size_t)s*64 + lane];
          }
        }
      }
      float dvd = dinv[dg];
      acc += dvd*dvd * h[(size_t)dg*64 + lane];
      agg[(size_t)dg*64 + lane] = acc;
    } else {
      float ax=0.f, ay=0.f;
      for(int b=e0;b<e1;b+=64){
        int mm = e1-b; if(mm>64) mm=64;
        long long pk = (lane<mm) ? ec[b+lane] : 0;
        int mr = (mm+7) & ~7;
        for(int jj=0;jj<mr;jj+=8){
          #pragma unroll
          for(int u=0;u<8;u++){
            long long p = __shfl(pk, jj+u, 64);
            int s = (int)(p & 0xffffffffLL);
            float c = __int_as_float((int)(p>>32));
            float2 hv = *(const float2*)(h + (size_t)s*HDIM + 2*lane);
            ax += c*hv.x; ay += c*hv.y;
          }
        }
      }
      float dvd = dinv[dg];
      float sl = dvd*dvd;
      float2 hv = *(const float2*)(h + (size_t)dg*HDIM + 2*lane);
      ax += sl*hv.x; ay += sl*hv.y;
      float2 o; o.x=ax; o.y=ay;
      *(float2*)(agg + (size_t)dg*HDIM + 2*lane) = o;
    }
  }
}

// ---------------- fp32 GEMM (64 rows x 128 cols / block) + bias + BN + ReLU + score ----------------
template<int KIN>
__global__ __launch_bounds__(256) void k_gemm(const float* __restrict__ Ain,
    const float* __restrict__ Wm, const float* __restrict__ bias,
    const float* __restrict__ gamma, const float* __restrict__ beta,
    const float* __restrict__ mean, const float* __restrict__ var,
    const float* __restrict__ pw, const float* __restrict__ invn_p,
    float* __restrict__ hc, float* __restrict__ score){
  __shared__ float As[64*68];    // row-major [row][k], stride 68
  __shared__ float Bs[64*128];   // [k][col]
  int t = threadIdx.x;
  int tx = t & 31, ty = t >> 5;  // thread: rows ty*8..+7, cols tx*4..+3
  int r0 = blockIdx.x * 64;
  float acc[8][4];
  #pragma unroll
  for(int j=0;j<8;j++){
    #pragma unroll
    for(int i=0;i<4;i++) acc[j][i]=0.f;
  }
  for(int k0=0;k0<KIN;k0+=64){
    #pragma unroll
    for(int p=0;p<16;p++){             // stage A 64x64 (coalesced, conflict-free)
      int idx = p*256 + t;
      int kk = idx & 63, rr = idx >> 6;
      As[rr*68 + kk] = Ain[(size_t)(r0+rr)*KIN + k0 + kk];
    }
    #pragma unroll
    for(int p=0;p<32;p++){             // stage B 64x128
      int idx = p*256 + t;
      int kk = idx >> 7, cc = idx & 127;
      Bs[kk*128 + cc] = Wm[(size_t)(k0+kk)*128 + cc];
    }
    __syncthreads();
    #pragma unroll 4
    for(int kk=0;kk<64;kk+=2){
      float4 b0 = *(float4*)&Bs[kk*128 + tx*4];
      float4 b1 = *(float4*)&Bs[(kk+1)*128 + tx*4];
      #pragma unroll
      for(int j=0;j<8;j++){
        float2 a = *(float2*)&As[(ty*8+j)*68 + kk];
        acc[j][0] += a.x*b0.x; acc[j][1] += a.x*b0.y;
        acc[j][2] += a.x*b0.z; acc[j][3] += a.x*b0.w;
        acc[j][0] += a.y*b1.x; acc[j][1] += a.y*b1.y;
        acc[j][2] += a.y*b1.z; acc[j][3] += a.y*b1.w;
      }
    }
    __syncthreads();
  }
  // epilogue: bias + BN + ReLU, write hc, score = tanh(dot(hc,pw)*invnorm)
  float invn = invn_p[0];
  float bi[4], scv[4], bt[4], mn[4], pwv[4];
  #pragma unroll
  for(int i=0;i<4;i++){
    int c = tx*4+i;
    bi[i]  = bias[c];
    scv[i] = gamma[c] * (1.0f/sqrtf(var[c] + BNEPS));
    bt[i]  = beta[c];
    mn[i]  = mean[c];
    pwv[i] = pw[c];
  }
  #pragma unroll
  for(int j=0;j<8;j++){
    int row = r0 + ty*8 + j;
    float v0 = fmaxf((acc[j][0]+bi[0]-mn[0])*scv[0]+bt[0], 0.f);
    float v1 = fmaxf((acc[j][1]+bi[1]-mn[1])*scv[1]+bt[1], 0.f);
    float v2 = fmaxf((acc[j][2]+bi[2]-mn[2])*scv[2]+bt[2], 0.f);
    float v3 = fmaxf((acc[j][3]+bi[3]-mn[3])*scv[3]+bt[3], 0.f);
    float4 o; o.x=v0; o.y=v1; o.z=v2; o.w=v3;
    *(float4*)(hc + (size_t)row*HDIM + tx*4) = o;
    float p = v0*pwv[0]+v1*pwv[1]+v2*pwv[2]+v3*pwv[3];
    #pragma unroll
    for(int m=16;m>=1;m>>=1) p += __shfl_xor(p, m, 64);
    if(tx==0) score[row] = tanhf(p * invn);
  }
}

// ---------------- per-graph top-k: bitonic sort (score desc, idx asc) ----------------
__global__ __launch_bounds__(512) void k_topk(int n, int k, int P,
    const float* __restrict__ score, int* __restrict__ perm, float* __restrict__ vals,
    int* __restrict__ inv){
  int g = blockIdx.x, t = threadIdx.x;
  __shared__ float s[1024];
  __shared__ int  id[1024];
  for(int i=t;i<P;i+=512){
    s[i]  = (i<n) ? score[g*n+i] : -FLT_MAX;
    id[i] = i;
  }
  __syncthreads();
  for(int k2=2;k2<=P;k2<<=1){
    for(int j=k2>>1;j>0;j>>=1){
      for(int i=t;i<P;i+=512){
        int ixj = i ^ j;
        if(ixj > i){
          bool desc = ((i & k2) == 0);
          float si = s[i], sx = s[ixj];
          int ii = id[i], ix = id[ixj];
          bool pre = (si > sx) || (si == sx && ii < ix);  // i precedes in desc order
          if(desc ? !pre : pre){ s[i]=sx; s[ixj]=si; id[i]=ix; id[ixj]=ii; }
        }
      }
      __syncthreads();
    }
  }
  for(int i=t;i<n;i+=512){
    int idx = id[i];
    if(i<k){ perm[g*k+i]=idx; vals[g*k+i]=s[i]; inv[g*n+idx]=g*k+i; }
    else inv[g*n+idx] = -1;
  }
}

// ---------------- edge remap ----------------
__global__ void k_remap(const int* __restrict__ inv, const int* __restrict__ si,
    const int* __restrict__ di, const float* __restrict__ wf,
    int* __restrict__ so, int* __restrict__ dou, float* __restrict__ wo){
  int e = blockIdx.x*256 + threadIdx.x;
  if(e >= NE) return;
  int s = si[e], d = di[e];
  float w = wf[e];
  int is = inv[s], idd = inv[d];
  bool ok = (w != 0.f) && (is >= 0) && (idd >= 0);
  so[e]  = ok ? is  : 0;
  dou[e] = ok ? idd : 0;
  wo[e]  = ok ? w   : 0.f;
}

// ---------------- gather h_next = hc[perm]*vals, partial mean/max pooling ----------------
#define POOL_NB 32
__global__ __launch_bounds__(256) void k_gatherpool(int n, int k,
    const float* __restrict__ hc, const int* __restrict__ perm, const float* __restrict__ vals,
    float* __restrict__ hnext, float* __restrict__ sumstage, unsigned* __restrict__ maxstage){
  int g = blockIdx.x & 63;
  int chunk = blockIdx.x >> 6;
  int wid = threadIdx.x >> 6, lane = threadIdx.x & 63;
  float2 psum; psum.x = 0.f; psum.y = 0.f;
  float2 pmax; pmax.x = -FLT_MAX; pmax.y = -FLT_MAX;
  for(int j = chunk*4 + wid; j < k; j += POOL_NB*4){
    int idx = perm[g*k+j];
    float v = vals[g*k+j];
    float2 hv = *(const float2*)(hc + (size_t)(g*n+idx)*HDIM + 2*lane);
    float2 o; o.x = hv.x*v; o.y = hv.y*v;
    *(float2*)(hnext + (size_t)(g*k+j)*HDIM + 2*lane) = o;
    psum.x += o.x; psum.y += o.y;
    pmax.x = fmaxf(pmax.x, o.x); pmax.y = fmaxf(pmax.y, o.y);
  }
  __shared__ float ss[4][128];
  __shared__ float sm[4][128];
  *(float2*)&ss[wid][2*lane] = psum;
  *(float2*)&sm[wid][2*lane] = pmax;
  __syncthreads();
  int t = threadIdx.x;
  if(t < 128){
    float s = (ss[0][t]+ss[1][t]) + (ss[2][t]+ss[3][t]);
    float m = fmaxf(fmaxf(sm[0][t], sm[1][t]), fmaxf(sm[2][t], sm[3][t]));
    atomicAdd(&sumstage[g*HDIM + t], s);
    atomicMax(&maxstage[g*HDIM + t], ford(m));
  }
}

// ---------------- fold pooling staging into flats, reset staging ----------------
__global__ void k_poolmerge(int k, float* __restrict__ flats,
    float* __restrict__ sumstage, unsigned* __restrict__ maxstage){
  int g = blockIdx.x, t = threadIdx.x;    // 64 blocks x 128 threads
  float s = sumstage[g*HDIM + t];
  float m = funord(maxstage[g*HDIM + t]);
  flats[g*256 + t]       += s / (float)k;
  flats[g*256 + 128 + t] += m;
  sumstage[g*HDIM + t] = 0.f;
  maxstage[g*HDIM + t] = FORD_NEGMAX;
}

// ---------------- MLP head ----------------
__global__ __launch_bounds__(512) void k_head(const float* __restrict__ flats,
    const float* __restrict__ d1w, const float* __restrict__ d1b,
    const float* __restrict__ d2w, const float* __restrict__ d2b, float* __restrict__ out){
  int g = blockIdx.x, j = threadIdx.x;
  __shared__ float fl[256];
  __shared__ float hd[512];
  for(int i=j;i<256;i+=512) fl[i] = flats[g*256+i];
  __syncthreads();
  float acc = d1b[j];
  for(int i=0;i<256;i++) acc += fl[i]*d1w[i*512+j];
  hd[j] = fmaxf(acc, 0.f);
  __syncthreads();
  if(j < 10){
    float a = d2b[j];
    for(int i=0;i<512;i++) a += hd[i]*d2w[i*10+j];
    out[g*10+j] = a;
  }
}

extern "C" void kernel_launch(void* const* d_in, const int* in_sizes, int n_in,
                              void* d_out, int out_size, void* d_ws, size_t ws_size,
                              hipStream_t stream) {
  const float* x    = (const float*)d_in[0];
  const int* ei     = (const int*)d_in[1];
  const float* ew   = (const float*)d_in[3];
  const float* conv1w = (const float*)d_in[4];
  const float* convw  = (const float*)d_in[5];
  const float* convb  = (const float*)d_in[6];
  const float* bng    = (const float*)d_in[7];
  const float* bnb    = (const float*)d_in[8];
  const float* bnm    = (const float*)d_in[9];
  const float* bnv    = (const float*)d_in[10];
  const float* poolw  = (const float*)d_in[11];
  const float* d1w    = (const float*)d_in[12];
  const float* d1b    = (const float*)d_in[13];
  const float* d2w    = (const float*)d_in[14];
  const float* d2b    = (const float*)d_in[15];
  float* out = (float*)d_out;

  char* w = (char*)d_ws;
  float* hc    = (float*)w; w += (size_t)64000*128*4;   // agg(1..5)/gemm in-place + layer0 gemm out
  float* agg0  = (float*)w; w += (size_t)64000*64*4;    // layer0 aggregation (64 cols)
  float* hbuf  = (float*)w; w += (size_t)51200*128*4;   // pooled features (layer input 1..5)
  int*   csrc  = (int*)w;   w += (size_t)NE*4;
  int*   cdst  = (int*)w;   w += (size_t)NE*4;
  float* cwe   = (float*)w; w += (size_t)NE*4;
  long long* ecpk = (long long*)w; w += (size_t)NE*8;   // packed (coef, src) per edge, dst-sorted
  int*   rp    = (int*)w;   w += (size_t)64*1008*4;
  float* dinv  = (float*)w; w += (size_t)64000*4;
  float* score = (float*)w; w += (size_t)64000*4;
  int*   perm  = (int*)w;   w += (size_t)51200*4;
  float* vals  = (float*)w; w += (size_t)51200*4;
  int*   inv   = (int*)w;   w += (size_t)64000*4;
  float* flats = (float*)w; w += (size_t)64*256*4;
  float* invno = (float*)w; w += 64;
  float* sumstage = (float*)w; w += (size_t)NGR*HDIM*4;
  unsigned* maxstage = (unsigned*)w; w += (size_t)NGR*HDIM*4;

  hipMemsetAsync(flats, 0, 64*256*4, stream);
  k_invnorm<<<6,128,0,stream>>>(poolw, invno);
  k_poolinit<<<(NGR*HDIM+255)/256,256,0,stream>>>(sumstage, maxstage);

  const int ns[6]={1000,800,640,512,410,328};
  const int ks[6]={800,640,512,410,328,263};

  // ---- layer 0 (input = x, 64 cols) ----
  k_csr<<<64,512,0,stream>>>(1000, ei, ei+NE, ew, rp, ecpk, dinv);
  k_agg<1><<<64*32,256,0,stream>>>(1000, rp, ecpk, dinv, x, agg0);
  k_gemm<64><<<1000,256,0,stream>>>(agg0, conv1w, convb, bng, bnb, bnm, bnv, poolw, invno, hc, score);
  k_topk<<<64,512,0,stream>>>(1000, 800, 1024, score, perm, vals, inv);
  k_remap<<<(NE+255)/256,256,0,stream>>>(inv, ei, ei+NE, ew, csrc, cdst, cwe);
  k_gatherpool<<<64*POOL_NB,256,0,stream>>>(1000, 800, hc, perm, vals, hbuf, sumstage, maxstage);
  k_poolmerge<<<64,128,0,stream>>>(800, flats, sumstage, maxstage);

  // ---- layers 1..5 ----
  for(int i=1;i<6;i++){
    int n = ns[i], k = ks[i];
    k_csr<<<64,512,0,stream>>>(n, csrc, cdst, cwe, rp, ecpk, dinv);
    k_agg<0><<<64*32,256,0,stream>>>(n, rp, ecpk, dinv, hbuf, hc);
    k_gemm<128><<<n,256,0,stream>>>(hc, convw+(size_t)(i-1)*128*128, convb+i*128, bng+i*128,
                                    bnb+i*128, bnm+i*128, bnv+i*128, poolw+i*128, invno+i, hc, score);
    int P = (n > 512) ? 1024 : 512;
    k_topk<<<64,512,0,stream>>>(n, k, P, score, perm, vals, inv);
    if(i<5) k_remap<<<(NE+255)/256,256,0,stream>>>(inv, csrc, cdst, cwe, csrc, cdst, cwe);
    k_gatherpool<<<64*POOL_NB,256,0,stream>>>(n, k, hc, perm, vals, hbuf, sumstage, maxstage);
    k_poolmerge<<<64,128,0,stream>>>(k, flats, sumstage, maxstage);
  }

  k_head<<<64,512,0,stream>>>(flats, d1w, d1b, d2w, d2b, out);
}

// Round 5
// 794.042 us; speedup vs baseline: 2.3569x; 1.0944x over previous
//
#include <hip/hip_runtime.h>
#include <float.h>
#include <math.h>

#define NGR 64        // graphs
#define NPG0 1000     // original nodes per graph
#define HDIM 128
#define EG 16000      // edges per graph
#define NE (NGR*EG)   // 1,024,000
#define RPS 1008      // rp row stride
#define BNEPS 1e-5f

// monotone float<->uint order mapping (no NaNs in this workload)
__device__ __forceinline__ unsigned ford(float x){
  unsigned u = __float_as_uint(x);
  return (u & 0x80000000u) ? ~u : (u | 0x80000000u);
}
__device__ __forceinline__ float funord(unsigned u){
  return (u & 0x80000000u) ? __uint_as_float(u ^ 0x80000000u) : __uint_as_float(~u);
}
#define FORD_NEGMAX 0x00800000u   // ford(-FLT_MAX)

// ---------------- invnorm of pool_w rows (6 layers) ----------------
__global__ void k_invnorm(const float* __restrict__ pw, float* __restrict__ invnorm){
  int i = blockIdx.x;                  // layer
  int t = threadIdx.x;                 // 128 threads
  float v = pw[i*HDIM + t];
  float s = v*v;
  #pragma unroll
  for(int o=32;o>0;o>>=1) s += __shfl_down(s, o, 64);
  __shared__ float red[2];
  if((t & 63)==0) red[t>>6] = s;
  __syncthreads();
  if(t==0) invnorm[i] = 1.0f / sqrtf(red[0]+red[1]);
}

// ---------------- init pooling staging buffers ----------------
__global__ void k_poolinit(float* __restrict__ sumstage, unsigned* __restrict__ maxstage){
  int i = blockIdx.x*256 + threadIdx.x;   // 64*128 = 8192 elements
  if(i < NGR*HDIM){ sumstage[i] = 0.f; maxstage[i] = FORD_NEGMAX; }
}

// ---------------- ONE-TIME CSR build in original node ids (edge-parallel) ----------------
__global__ void k_count0(const int* __restrict__ dst, const float* __restrict__ we,
    int* __restrict__ cnt, float* __restrict__ deg){
  int e = blockIdx.x*256 + threadIdx.x;
  if(e >= NE) return;
  int d = dst[e];
  atomicAdd(&cnt[d], 1);
  atomicAdd(&deg[d], we[e]);
}

__global__ __launch_bounds__(512) void k_scan0(const int* __restrict__ cnt,
    const float* __restrict__ deg, int* __restrict__ rp, int* __restrict__ cursor,
    float* __restrict__ dinvz){
  int g = blockIdx.x, t = threadIdx.x;
  __shared__ int sc[2][1024];
  for(int i=t;i<1024;i+=512) sc[0][i] = (i<NPG0) ? cnt[g*NPG0+i] : 0;
  __syncthreads();
  int buf = 0;
  for(int d=1; d<1024; d<<=1){
    for(int i=t;i<1024;i+=512){
      int v = sc[buf][i];
      if(i>=d) v += sc[buf][i-d];
      sc[buf^1][i] = v;
    }
    __syncthreads();
    buf ^= 1;
  }
  for(int i=t;i<=NPG0;i+=512) rp[g*RPS+i] = (i==0) ? 0 : sc[buf][i-1];
  for(int i=t;i<NPG0;i+=512){
    cursor[g*NPG0+i] = (i==0) ? 0 : sc[buf][i-1];
    dinvz[g*NPG0+i] = 1.0f / sqrtf(deg[g*NPG0+i] + 1.0f);
  }
}

// ec record = (float w)<<32 | src_orig  (static for whole run)
__global__ void k_scatter0(const int* __restrict__ src, const int* __restrict__ dst,
    const float* __restrict__ we, int* __restrict__ cursor, long long* __restrict__ ec){
  int e = blockIdx.x*256 + threadIdx.x;
  if(e >= NE) return;
  int d = dst[e], s = src[e];
  float w = we[e];
  int pos = atomicAdd(&cursor[d], 1);          // graph-local offset
  int g = d / NPG0;
  ec[(size_t)g*EG + pos] = (((long long)__float_as_int(w))<<32) | (unsigned)s;
}

// ---------------- per-layer weighted degree over alive srcs ----------------
// alive indicator: dinvz[node] != 0 (topk zeroes dropped nodes; values stay nonzero
// for alive nodes across the in-kernel update, so read/write overlap is benign).
__global__ __launch_bounds__(256) void k_deg(int n, const int* __restrict__ nlist,
    const int* __restrict__ rp, const long long* __restrict__ ec,
    float* __restrict__ dinvz){
  int g = blockIdx.x & 63, chunk = blockIdx.x >> 6;
  int wid = threadIdx.x >> 6, lane = threadIdx.x & 63;
  const int wpg = (gridDim.x >> 6) * 4;
  for(int j = chunk*4 + wid; j < n; j += wpg){
    int d  = nlist[g*n + j];
    int ld = d - g*NPG0;
    int e0 = rp[g*RPS+ld], e1 = rp[g*RPS+ld+1];
    float deg = 0.f;
    for(int b=e0+lane; b<e1; b+=64){
      long long rec = ec[(size_t)g*EG + b];
      int s = (int)(rec & 0xffffffffLL);
      float w = __int_as_float((int)(rec>>32));
      if(dinvz[s] != 0.f) deg += w;
    }
    #pragma unroll
    for(int o=32;o>0;o>>=1) deg += __shfl_xor(deg, o, 64);
    if(lane==0) dinvz[d] = 1.0f / sqrtf(deg + 1.0f);
  }
}

// ---------------- aggregation over original-id buckets ----------------
// agg[compact dst row] = dvd * sum_e (w*dinvz[src]) * h[src] + dvd^2 * h[d]
// Dead-src edges have dinvz[src]==0 -> coefficient 0 -> wave-uniform skip.
template<int L0>
__global__ __launch_bounds__(256) void k_agg(int n, const int* __restrict__ nlist,
    const int* __restrict__ rp, const long long* __restrict__ ec,
    const float* __restrict__ dinvz, const float* __restrict__ h,
    float* __restrict__ agg){
  int g = blockIdx.x & 63;            // graph-major: XCD locality
  int chunk = blockIdx.x >> 6;
  int wid = threadIdx.x >> 6, lane = threadIdx.x & 63;
  const int wpg = (gridDim.x >> 6) * 4;
  for(int j = chunk*4 + wid; j < n; j += wpg){
    int cg = g*n + j;                               // compact row
    int d  = L0 ? (g*NPG0 + j) : nlist[cg];         // original id
    int ld = d - g*NPG0;
    int e0 = rp[g*RPS+ld], e1 = rp[g*RPS+ld+1];
    float dvd = dinvz[d];
    if(L0){
      float acc = 0.f;
      for(int b=e0;b<e1;b+=64){
        int mm = e1-b; if(mm>64) mm=64;
        long long rec = (lane<mm) ? ec[(size_t)g*EG + b + lane] : 0;
        int   sl = (int)(rec & 0xffffffffLL);
        float cl = __int_as_float((int)(rec>>32)) * dinvz[sl];
        long long pk = (((long long)__float_as_int(cl))<<32) | (unsigned)sl;
        int mr = (mm+7) & ~7;
        for(int jj=0;jj<mr;jj+=8){
          #pragma unroll
          for(int u=0;u<8;u++){
            long long p = __shfl(pk, jj+u, 64);
            float c = __int_as_float((int)(p>>32));
            if(c != 0.f){
              int s = (int)(p & 0xffffffffLL);
              acc += c * h[(size_t)s*64 + lane];
            }
          }
        }
      }
      acc = dvd*acc + dvd*dvd*h[(size_t)d*64 + lane];
      agg[(size_t)cg*64 + lane] = acc;
    } else {
      float ax=0.f, ay=0.f;
      for(int b=e0;b<e1;b+=64){
        int mm = e1-b; if(mm>64) mm=64;
        long long rec = (lane<mm) ? ec[(size_t)g*EG + b + lane] : 0;
        int   sl = (int)(rec & 0xffffffffLL);
        float cl = __int_as_float((int)(rec>>32)) * dinvz[sl];
        long long pk = (((long long)__float_as_int(cl))<<32) | (unsigned)sl;
        int mr = (mm+7) & ~7;
        for(int jj=0;jj<mr;jj+=8){
          #pragma unroll
          for(int u=0;u<8;u++){
            long long p = __shfl(pk, jj+u, 64);
            float c = __int_as_float((int)(p>>32));
            if(c != 0.f){
              int s = (int)(p & 0xffffffffLL);
              float2 hv = *(const float2*)(h + (size_t)s*HDIM + 2*lane);
              ax += c*hv.x; ay += c*hv.y;
            }
          }
        }
      }
      float2 hv = *(const float2*)(h + (size_t)d*HDIM + 2*lane);
      float2 o; o.x = dvd*ax + dvd*dvd*hv.x; o.y = dvd*ay + dvd*dvd*hv.y;
      *(float2*)(agg + (size_t)cg*HDIM + 2*lane) = o;
    }
  }
}

// ---------------- fp32 GEMM (64 rows x 128 cols / block) + bias + BN + ReLU + score ----------------
template<int KIN>
__global__ __launch_bounds__(256) void k_gemm(const float* __restrict__ Ain,
    const float* __restrict__ Wm, const float* __restrict__ bias,
    const float* __restrict__ gamma, const float* __restrict__ beta,
    const float* __restrict__ mean, const float* __restrict__ var,
    const float* __restrict__ pw, const float* __restrict__ invn_p,
    float* __restrict__ hc, float* __restrict__ score){
  __shared__ float As[64*68];    // row-major [row][k], stride 68
  __shared__ float Bs[64*128];   // [k][col]
  int t = threadIdx.x;
  int tx = t & 31, ty = t >> 5;  // thread: rows ty*8..+7, cols tx*4..+3
  int r0 = blockIdx.x * 64;
  float acc[8][4];
  #pragma unroll
  for(int j=0;j<8;j++){
    #pragma unroll
    for(int i=0;i<4;i++) acc[j][i]=0.f;
  }
  for(int k0=0;k0<KIN;k0+=64){
    #pragma unroll
    for(int p=0;p<16;p++){             // stage A 64x64 (coalesced, conflict-free)
      int idx = p*256 + t;
      int kk = idx & 63, rr = idx >> 6;
      As[rr*68 + kk] = Ain[(size_t)(r0+rr)*KIN + k0 + kk];
    }
    #pragma unroll
    for(int p=0;p<32;p++){             // stage B 64x128
      int idx = p*256 + t;
      int kk = idx >> 7, cc = idx & 127;
      Bs[kk*128 + cc] = Wm[(size_t)(k0+kk)*128 + cc];
    }
    __syncthreads();
    #pragma unroll 4
    for(int kk=0;kk<64;kk+=2){
      float4 b0 = *(float4*)&Bs[kk*128 + tx*4];
      float4 b1 = *(float4*)&Bs[(kk+1)*128 + tx*4];
      #pragma unroll
      for(int j=0;j<8;j++){
        float2 a = *(float2*)&As[(ty*8+j)*68 + kk];
        acc[j][0] += a.x*b0.x; acc[j][1] += a.x*b0.y;
        acc[j][2] += a.x*b0.z; acc[j][3] += a.x*b0.w;
        acc[j][0] += a.y*b1.x; acc[j][1] += a.y*b1.y;
        acc[j][2] += a.y*b1.z; acc[j][3] += a.y*b1.w;
      }
    }
    __syncthreads();
  }
  // epilogue: bias + BN + ReLU, write hc, score = tanh(dot(hc,pw)*invnorm)
  float invn = invn_p[0];
  float bi[4], scv[4], bt[4], mn[4], pwv[4];
  #pragma unroll
  for(int i=0;i<4;i++){
    int c = tx*4+i;
    bi[i]  = bias[c];
    scv[i] = gamma[c] * (1.0f/sqrtf(var[c] + BNEPS));
    bt[i]  = beta[c];
    mn[i]  = mean[c];
    pwv[i] = pw[c];
  }
  #pragma unroll
  for(int j=0;j<8;j++){
    int row = r0 + ty*8 + j;
    float v0 = fmaxf((acc[j][0]+bi[0]-mn[0])*scv[0]+bt[0], 0.f);
    float v1 = fmaxf((acc[j][1]+bi[1]-mn[1])*scv[1]+bt[1], 0.f);
    float v2 = fmaxf((acc[j][2]+bi[2]-mn[2])*scv[2]+bt[2], 0.f);
    float v3 = fmaxf((acc[j][3]+bi[3]-mn[3])*scv[3]+bt[3], 0.f);
    float4 o; o.x=v0; o.y=v1; o.z=v2; o.w=v3;
    *(float4*)(hc + (size_t)row*HDIM + tx*4) = o;
    float p = v0*pwv[0]+v1*pwv[1]+v2*pwv[2]+v3*pwv[3];
    #pragma unroll
    for(int m=16;m>=1;m>>=1) p += __shfl_xor(p, m, 64);
    if(tx==0) score[row] = tanhf(p * invn);
  }
}

// ---------------- per-graph top-k: bitonic sort (score desc, idx asc) ----------------
// Also: compose orig-id node list for next layer; zero dinvz of dropped nodes.
__global__ __launch_bounds__(512) void k_topk(int n, int k, int P,
    const float* __restrict__ score, const int* __restrict__ curlist,
    int* __restrict__ perm, float* __restrict__ vals,
    int* __restrict__ nextlist, float* __restrict__ dinvz){
  int g = blockIdx.x, t = threadIdx.x;
  __shared__ float s[1024];
  __shared__ int  id[1024];
  for(int i=t;i<P;i+=512){
    s[i]  = (i<n) ? score[g*n+i] : -FLT_MAX;
    id[i] = i;
  }
  __syncthreads();
  for(int k2=2;k2<=P;k2<<=1){
    for(int j=k2>>1;j>0;j>>=1){
      for(int i=t;i<P;i+=512){
        int ixj = i ^ j;
        if(ixj > i){
          bool desc = ((i & k2) == 0);
          float si = s[i], sx = s[ixj];
          int ii = id[i], ix = id[ixj];
          bool pre = (si > sx) || (si == sx && ii < ix);  // i precedes in desc order
          if(desc ? !pre : pre){ s[i]=sx; s[ixj]=si; id[i]=ix; id[ixj]=ii; }
        }
      }
      __syncthreads();
    }
  }
  for(int i=t;i<n;i+=512){
    int idx = id[i];
    int orig = curlist ? curlist[g*n+idx] : (g*NPG0 + idx);
    if(i<k){
      perm[g*k+i]=idx; vals[g*k+i]=s[i]; nextlist[g*k+i]=orig;
    } else {
      dinvz[orig] = 0.f;               // node dies (alive sets nest)
    }
  }
}

// ---------------- gather h_orig[orig] = hc[perm]*vals, partial mean/max pooling ----------------
#define POOL_NB 32
__global__ __launch_bounds__(256) void k_gatherpool(int n, int k,
    const float* __restrict__ hc, const int* __restrict__ perm, const float* __restrict__ vals,
    const int* __restrict__ nextlist,
    float* __restrict__ horig, float* __restrict__ sumstage, unsigned* __restrict__ maxstage){
  int g = blockIdx.x & 63;
  int chunk = blockIdx.x >> 6;
  int wid = threadIdx.x >> 6, lane = threadIdx.x & 63;
  float2 psum; psum.x = 0.f; psum.y = 0.f;
  float2 pmax; pmax.x = -FLT_MAX; pmax.y = -FLT_MAX;
  for(int j = chunk*4 + wid; j < k; j += POOL_NB*4){
    int idx = perm[g*k+j];
    float v = vals[g*k+j];
    int orig = nextlist[g*k+j];
    float2 hv = *(const float2*)(hc + (size_t)(g*n+idx)*HDIM + 2*lane);
    float2 o; o.x = hv.x*v; o.y = hv.y*v;
    *(float2*)(horig + (size_t)orig*HDIM + 2*lane) = o;
    psum.x += o.x; psum.y += o.y;
    pmax.x = fmaxf(pmax.x, o.x); pmax.y = fmaxf(pmax.y, o.y);
  }
  __shared__ float ss[4][128];
  __shared__ float sm[4][128];
  *(float2*)&ss[wid][2*lane] = psum;
  *(float2*)&sm[wid][2*lane] = pmax;
  __syncthreads();
  int t = threadIdx.x;
  if(t < 128){
    float s = (ss[0][t]+ss[1][t]) + (ss[2][t]+ss[3][t]);
    float m = fmaxf(fmaxf(sm[0][t], sm[1][t]), fmaxf(sm[2][t], sm[3][t]));
    atomicAdd(&sumstage[g*HDIM + t], s);
    atomicMax(&maxstage[g*HDIM + t], ford(m));
  }
}

// ---------------- fold pooling staging into flats, reset staging ----------------
__global__ void k_poolmerge(int k, float* __restrict__ flats,
    float* __restrict__ sumstage, unsigned* __restrict__ maxstage){
  int g = blockIdx.x, t = threadIdx.x;    // 64 blocks x 128 threads
  float s = sumstage[g*HDIM + t];
  float m = funord(maxstage[g*HDIM + t]);
  flats[g*256 + t]       += s / (float)k;
  flats[g*256 + 128 + t] += m;
  sumstage[g*HDIM + t] = 0.f;
  maxstage[g*HDIM + t] = FORD_NEGMAX;
}

// ---------------- MLP head ----------------
__global__ __launch_bounds__(512) void k_head(const float* __restrict__ flats,
    const float* __restrict__ d1w, const float* __restrict__ d1b,
    const float* __restrict__ d2w, const float* __restrict__ d2b, float* __restrict__ out){
  int g = blockIdx.x, j = threadIdx.x;
  __shared__ float fl[256];
  __shared__ float hd[512];
  for(int i=j;i<256;i+=512) fl[i] = flats[g*256+i];
  __syncthreads();
  float acc = d1b[j];
  for(int i=0;i<256;i++) acc += fl[i]*d1w[i*512+j];
  hd[j] = fmaxf(acc, 0.f);
  __syncthreads();
  if(j < 10){
    float a = d2b[j];
    for(int i=0;i<512;i++) a += hd[i]*d2w[i*10+j];
    out[g*10+j] = a;
  }
}

extern "C" void kernel_launch(void* const* d_in, const int* in_sizes, int n_in,
                              void* d_out, int out_size, void* d_ws, size_t ws_size,
                              hipStream_t stream) {
  const float* x    = (const float*)d_in[0];
  const int* ei     = (const int*)d_in[1];
  const float* ew   = (const float*)d_in[3];
  const float* conv1w = (const float*)d_in[4];
  const float* convw  = (const float*)d_in[5];
  const float* convb  = (const float*)d_in[6];
  const float* bng    = (const float*)d_in[7];
  const float* bnb    = (const float*)d_in[8];
  const float* bnm    = (const float*)d_in[9];
  const float* bnv    = (const float*)d_in[10];
  const float* poolw  = (const float*)d_in[11];
  const float* d1w    = (const float*)d_in[12];
  const float* d1b    = (const float*)d_in[13];
  const float* d2w    = (const float*)d_in[14];
  const float* d2b    = (const float*)d_in[15];
  float* out = (float*)d_out;

  char* w = (char*)d_ws;
  float* horig = (float*)w; w += (size_t)64000*128*4;   // features by original node id
  float* hc    = (float*)w; w += (size_t)64000*128*4;   // agg / gemm output (compact rows)
  float* agg0  = (float*)w; w += (size_t)64000*64*4;    // layer-0 aggregation (64 cols)
  long long* ec = (long long*)w; w += (size_t)NE*8;     // static (w, src_orig), dst-bucketed
  int*   rp    = (int*)w;   w += (size_t)NGR*RPS*4;
  int*   cnt   = (int*)w;   w += (size_t)64000*4;
  int*   cursor= (int*)w;   w += (size_t)64000*4;
  float* deg   = (float*)w; w += (size_t)64000*4;
  float* dinvz = (float*)w; w += (size_t)64000*4;       // 0 == node dead
  float* score = (float*)w; w += (size_t)64000*4;
  int*   perm  = (int*)w;   w += (size_t)51200*4;
  float* vals  = (float*)w; w += (size_t)51200*4;
  int*   listA = (int*)w;   w += (size_t)51200*4;
  int*   listB = (int*)w;   w += (size_t)51200*4;
  float* flats = (float*)w; w += (size_t)64*256*4;
  float* invno = (float*)w; w += 64;
  float* sumstage = (float*)w; w += (size_t)NGR*HDIM*4;
  unsigned* maxstage = (unsigned*)w; w += (size_t)NGR*HDIM*4;

  hipMemsetAsync(flats, 0, 64*256*4, stream);
  hipMemsetAsync(cnt, 0, 64000*4, stream);
  hipMemsetAsync(deg, 0, 64000*4, stream);
  k_invnorm<<<6,128,0,stream>>>(poolw, invno);
  k_poolinit<<<(NGR*HDIM+255)/256,256,0,stream>>>(sumstage, maxstage);

  const int ns[6]={1000,800,640,512,410,328};
  const int ks[6]={800,640,512,410,328,263};

  // ---- one-time CSR build (original ids) ----
  k_count0<<<(NE+255)/256,256,0,stream>>>(ei+NE, ew, cnt, deg);
  k_scan0<<<64,512,0,stream>>>(cnt, deg, rp, cursor, dinvz);
  k_scatter0<<<(NE+255)/256,256,0,stream>>>(ei, ei+NE, ew, cursor, ec);

  // ---- layer 0 (input = x, 64 cols) ----
  k_agg<1><<<64*32,256,0,stream>>>(1000, nullptr, rp, ec, dinvz, x, agg0);
  k_gemm<64><<<1000,256,0,stream>>>(agg0, conv1w, convb, bng, bnb, bnm, bnv, poolw, invno, hc, score);
  k_topk<<<64,512,0,stream>>>(1000, 800, 1024, score, nullptr, perm, vals, listA, dinvz);
  k_gatherpool<<<64*POOL_NB,256,0,stream>>>(1000, 800, hc, perm, vals, listA, horig, sumstage, maxstage);
  k_poolmerge<<<64,128,0,stream>>>(800, flats, sumstage, maxstage);

  // ---- layers 1..5 ----
  int* cur = listA; int* nxt = listB;
  for(int i=1;i<6;i++){
    int n = ns[i], k = ks[i];
    k_deg<<<64*32,256,0,stream>>>(n, cur, rp, ec, dinvz);
    k_agg<0><<<64*32,256,0,stream>>>(n, cur, rp, ec, dinvz, horig, hc);
    k_gemm<128><<<n,256,0,stream>>>(hc, convw+(size_t)(i-1)*128*128, convb+i*128, bng+i*128,
                                    bnb+i*128, bnm+i*128, bnv+i*128, poolw+i*128, invno+i, hc, score);
    int P = (n > 512) ? 1024 : 512;
    k_topk<<<64,512,0,stream>>>(n, k, P, score, cur, perm, vals, nxt, dinvz);
    k_gatherpool<<<64*POOL_NB,256,0,stream>>>(n, k, hc, perm, vals, nxt, horig, sumstage, maxstage);
    k_poolmerge<<<64,128,0,stream>>>(k, flats, sumstage, maxstage);
    int* tmp = cur; cur = nxt; nxt = tmp;
  }

  k_head<<<64,512,0,stream>>>(flats, d1w, d1b, d2w, d2b, out);
}

// Round 6
// 767.104 us; speedup vs baseline: 2.4397x; 1.0351x over previous
//
#include <hip/hip_runtime.h>
#include <float.h>
#include <math.h>

#define NGR 64        // graphs
#define NPG0 1000     // original nodes per graph
#define HDIM 128
#define EG 16000      // edges per graph
#define NE (NGR*EG)   // 1,024,000
#define RPS 1008      // rp row stride
#define BNEPS 1e-5f
#define POOL_NB 8

// monotone float<->uint order mapping (no NaNs in this workload)
__device__ __forceinline__ unsigned ford(float x){
  unsigned u = __float_as_uint(x);
  return (u & 0x80000000u) ? ~u : (u | 0x80000000u);
}
__device__ __forceinline__ float funord(unsigned u){
  return (u & 0x80000000u) ? __uint_as_float(u ^ 0x80000000u) : __uint_as_float(~u);
}
#define FORD_NEGMAX 0x00800000u   // ford(-FLT_MAX)

// ---------------- setup: invnorm (blocks 0..5) + staging init (blocks 6..197) ----------------
__global__ __launch_bounds__(256) void k_setup(const float* __restrict__ pw,
    float* __restrict__ invnorm, float* __restrict__ sumstage, unsigned* __restrict__ maxstage){
  if(blockIdx.x < 6){
    int i = blockIdx.x, t = threadIdx.x;
    __shared__ float red[2];
    if(t < 128){
      float v = pw[i*HDIM + t];
      float s = v*v;
      #pragma unroll
      for(int o=32;o>0;o>>=1) s += __shfl_down(s, o, 64);
      if((t & 63)==0) red[t>>6] = s;
    }
    __syncthreads();
    if(t==0) invnorm[i] = 1.0f / sqrtf(red[0]+red[1]);
  } else {
    int i = (blockIdx.x-6)*256 + threadIdx.x;   // 6*64*128 = 49152 elements
    if(i < 6*NGR*HDIM){ sumstage[i] = 0.f; maxstage[i] = FORD_NEGMAX; }
  }
}

// ---------------- build phase: per-graph-chunk LDS count + weighted degree (atomic-free out) ----------------
__global__ __launch_bounds__(256) void k_count0(const int* __restrict__ dst,
    const float* __restrict__ we, int* __restrict__ pcnt, float* __restrict__ pdeg){
  int g = blockIdx.x >> 2, sub = blockIdx.x & 3, t = threadIdx.x;
  __shared__ int   cnt[NPG0];
  __shared__ float degl[NPG0];
  for(int i=t;i<NPG0;i+=256){ cnt[i]=0; degl[i]=0.f; }
  __syncthreads();
  int base = g*EG + sub*4000;
  for(int idx=t; idx<4000; idx+=256){
    int e = base + idx;
    int ld = dst[e] - g*NPG0;
    atomicAdd(&cnt[ld], 1);
    atomicAdd(&degl[ld], we[e]);
  }
  __syncthreads();
  int p = blockIdx.x * NPG0;
  for(int i=t;i<NPG0;i+=256){ pcnt[p+i] = cnt[i]; pdeg[p+i] = degl[i]; }
}

__global__ __launch_bounds__(512) void k_scan0(const int* __restrict__ pcnt,
    const float* __restrict__ pdeg, int* __restrict__ rp, float* __restrict__ dinvz){
  int g = blockIdx.x, t = threadIdx.x;
  __shared__ int sc[2][1024];
  for(int i=t;i<1024;i+=512){
    int c = 0;
    if(i<NPG0){
      c = pcnt[(g*4+0)*NPG0+i] + pcnt[(g*4+1)*NPG0+i]
        + pcnt[(g*4+2)*NPG0+i] + pcnt[(g*4+3)*NPG0+i];
      float dg = pdeg[(g*4+0)*NPG0+i] + pdeg[(g*4+1)*NPG0+i]
               + pdeg[(g*4+2)*NPG0+i] + pdeg[(g*4+3)*NPG0+i];
      dinvz[g*NPG0+i] = 1.0f / sqrtf(dg + 1.0f);
    }
    sc[0][i] = c;
  }
  __syncthreads();
  int buf = 0;
  for(int d=1; d<1024; d<<=1){
    for(int i=t;i<1024;i+=512){
      int v = sc[buf][i];
      if(i>=d) v += sc[buf][i-d];
      sc[buf^1][i] = v;
    }
    __syncthreads();
    buf ^= 1;
  }
  for(int i=t;i<=NPG0;i+=512) rp[g*RPS+i] = (i==0) ? 0 : sc[buf][i-1];
}

// ---------------- scatter: per-graph LDS cursor (no global atomics) ----------------
// ec record = (float w)<<32 | src_orig  (static for whole run)
__global__ __launch_bounds__(1024) void k_scatter0(const int* __restrict__ src,
    const int* __restrict__ dst, const float* __restrict__ we,
    const int* __restrict__ rp, long long* __restrict__ ec){
  int g = blockIdx.x, t = threadIdx.x;
  __shared__ int cur[NPG0];
  for(int i=t;i<NPG0;i+=1024) cur[i] = rp[g*RPS+i];
  __syncthreads();
  int base = g*EG;
  for(int idx=t; idx<EG; idx+=1024){
    int e = base + idx;
    int ld = dst[e] - g*NPG0;
    int pos = atomicAdd(&cur[ld], 1);
    ec[(size_t)base + pos] = (((long long)__float_as_int(we[e]))<<32) | (unsigned)src[e];
  }
}

// ---------------- aggregation over original-id buckets ----------------
// agg[compact dst row] = dvd * sum_e (w*dinvz[src]) * h[src] + dvd^2 * h[d]
template<int L0>
__global__ __launch_bounds__(256) void k_agg(int n, const int* __restrict__ nlist,
    const int* __restrict__ rp, const long long* __restrict__ ec,
    const float* __restrict__ dinvz, const float* __restrict__ h,
    float* __restrict__ agg){
  int g = blockIdx.x & 63;            // graph-major: XCD locality
  int chunk = blockIdx.x >> 6;
  int wid = threadIdx.x >> 6, lane = threadIdx.x & 63;
  const int wpg = (gridDim.x >> 6) * 4;
  for(int j = chunk*4 + wid; j < n; j += wpg){
    int cg = g*n + j;                               // compact row
    int d  = L0 ? (g*NPG0 + j) : nlist[cg];         // original id
    int ld = d - g*NPG0;
    int e0 = rp[g*RPS+ld], e1 = rp[g*RPS+ld+1];
    float dvd = dinvz[d];
    if(L0){
      float acc = 0.f;
      for(int b=e0;b<e1;b+=64){
        int mm = e1-b; if(mm>64) mm=64;
        long long rec = (lane<mm) ? ec[(size_t)g*EG + b + lane] : 0;
        int   sl = (int)(rec & 0xffffffffLL);
        float cl = __int_as_float((int)(rec>>32)) * dinvz[sl];
        long long pk = (((long long)__float_as_int(cl))<<32) | (unsigned)sl;
        int mr = (mm+7) & ~7;
        for(int jj=0;jj<mr;jj+=8){
          #pragma unroll
          for(int u=0;u<8;u++){
            long long p = __shfl(pk, jj+u, 64);
            float c = __int_as_float((int)(p>>32));
            if(c != 0.f){
              int s = (int)(p & 0xffffffffLL);
              acc += c * h[(size_t)s*64 + lane];
            }
          }
        }
      }
      acc = dvd*acc + dvd*dvd*h[(size_t)d*64 + lane];
      agg[(size_t)cg*64 + lane] = acc;
    } else {
      float ax=0.f, ay=0.f;
      for(int b=e0;b<e1;b+=64){
        int mm = e1-b; if(mm>64) mm=64;
        long long rec = (lane<mm) ? ec[(size_t)g*EG + b + lane] : 0;
        int   sl = (int)(rec & 0xffffffffLL);
        float cl = __int_as_float((int)(rec>>32)) * dinvz[sl];
        long long pk = (((long long)__float_as_int(cl))<<32) | (unsigned)sl;
        int mr = (mm+7) & ~7;
        for(int jj=0;jj<mr;jj+=8){
          #pragma unroll
          for(int u=0;u<8;u++){
            long long p = __shfl(pk, jj+u, 64);
            float c = __int_as_float((int)(p>>32));
            if(c != 0.f){
              int s = (int)(p & 0xffffffffLL);
              float2 hv = *(const float2*)(h + (size_t)s*HDIM + 2*lane);
              ax += c*hv.x; ay += c*hv.y;
            }
          }
        }
      }
      float2 hv = *(const float2*)(h + (size_t)d*HDIM + 2*lane);
      float2 o; o.x = dvd*ax + dvd*dvd*hv.x; o.y = dvd*ay + dvd*dvd*hv.y;
      *(float2*)(agg + (size_t)cg*HDIM + 2*lane) = o;
    }
  }
}

// ---------------- fp32 GEMM (64 rows x 128 cols / block) + bias + BN + ReLU + score ----------------
template<int KIN>
__global__ __launch_bounds__(256) void k_gemm(const float* __restrict__ Ain,
    const float* __restrict__ Wm, const float* __restrict__ bias,
    const float* __restrict__ gamma, const float* __restrict__ beta,
    const float* __restrict__ mean, const float* __restrict__ var,
    const float* __restrict__ pw, const float* __restrict__ invn_p,
    float* __restrict__ hc, float* __restrict__ score){
  __shared__ float As[64*68];    // row-major [row][k], stride 68
  __shared__ float Bs[64*128];   // [k][col]
  int t = threadIdx.x;
  int tx = t & 31, ty = t >> 5;  // thread: rows ty*8..+7, cols tx*4..+3
  int r0 = blockIdx.x * 64;
  float acc[8][4];
  #pragma unroll
  for(int j=0;j<8;j++){
    #pragma unroll
    for(int i=0;i<4;i++) acc[j][i]=0.f;
  }
  for(int k0=0;k0<KIN;k0+=64){
    #pragma unroll
    for(int p=0;p<16;p++){             // stage A 64x64 (coalesced, conflict-free)
      int idx = p*256 + t;
      int kk = idx & 63, rr = idx >> 6;
      As[rr*68 + kk] = Ain[(size_t)(r0+rr)*KIN + k0 + kk];
    }
    #pragma unroll
    for(int p=0;p<32;p++){             // stage B 64x128
      int idx = p*256 + t;
      int kk = idx >> 7, cc = idx & 127;
      Bs[kk*128 + cc] = Wm[(size_t)(k0+kk)*128 + cc];
    }
    __syncthreads();
    #pragma unroll 4
    for(int kk=0;kk<64;kk+=2){
      float4 b0 = *(float4*)&Bs[kk*128 + tx*4];
      float4 b1 = *(float4*)&Bs[(kk+1)*128 + tx*4];
      #pragma unroll
      for(int j=0;j<8;j++){
        float2 a = *(float2*)&As[(ty*8+j)*68 + kk];
        acc[j][0] += a.x*b0.x; acc[j][1] += a.x*b0.y;
        acc[j][2] += a.x*b0.z; acc[j][3] += a.x*b0.w;
        acc[j][0] += a.y*b1.x; acc[j][1] += a.y*b1.y;
        acc[j][2] += a.y*b1.z; acc[j][3] += a.y*b1.w;
      }
    }
    __syncthreads();
  }
  // epilogue: bias + BN + ReLU, write hc, score = tanh(dot(hc,pw)*invnorm)
  float invn = invn_p[0];
  float bi[4], scv[4], bt[4], mn[4], pwv[4];
  #pragma unroll
  for(int i=0;i<4;i++){
    int c = tx*4+i;
    bi[i]  = bias[c];
    scv[i] = gamma[c] * (1.0f/sqrtf(var[c] + BNEPS));
    bt[i]  = beta[c];
    mn[i]  = mean[c];
    pwv[i] = pw[c];
  }
  #pragma unroll
  for(int j=0;j<8;j++){
    int row = r0 + ty*8 + j;
    float v0 = fmaxf((acc[j][0]+bi[0]-mn[0])*scv[0]+bt[0], 0.f);
    float v1 = fmaxf((acc[j][1]+bi[1]-mn[1])*scv[1]+bt[1], 0.f);
    float v2 = fmaxf((acc[j][2]+bi[2]-mn[2])*scv[2]+bt[2], 0.f);
    float v3 = fmaxf((acc[j][3]+bi[3]-mn[3])*scv[3]+bt[3], 0.f);
    float4 o; o.x=v0; o.y=v1; o.z=v2; o.w=v3;
    *(float4*)(hc + (size_t)row*HDIM + tx*4) = o;
    float p = v0*pwv[0]+v1*pwv[1]+v2*pwv[2]+v3*pwv[3];
    #pragma unroll
    for(int m=16;m>=1;m>>=1) p += __shfl_xor(p, m, 64);
    if(tx==0) score[row] = tanhf(p * invn);
  }
}

// ---------------- per-graph top-k: bitonic sort (score desc, idx asc) ----------------
// Also: compose orig-id node list for next layer; zero dinvz of dropped nodes.
__global__ __launch_bounds__(512) void k_topk(int n, int k, int P,
    const float* __restrict__ score, const int* __restrict__ curlist,
    int* __restrict__ perm, float* __restrict__ vals,
    int* __restrict__ nextlist, float* __restrict__ dinvz){
  int g = blockIdx.x, t = threadIdx.x;
  __shared__ float s[1024];
  __shared__ int  id[1024];
  for(int i=t;i<P;i+=512){
    s[i]  = (i<n) ? score[g*n+i] : -FLT_MAX;
    id[i] = i;
  }
  __syncthreads();
  for(int k2=2;k2<=P;k2<<=1){
    for(int j=k2>>1;j>0;j>>=1){
      for(int i=t;i<P;i+=512){
        int ixj = i ^ j;
        if(ixj > i){
          bool desc = ((i & k2) == 0);
          float si = s[i], sx = s[ixj];
          int ii = id[i], ix = id[ixj];
          bool pre = (si > sx) || (si == sx && ii < ix);  // i precedes in desc order
          if(desc ? !pre : pre){ s[i]=sx; s[ixj]=si; id[i]=ix; id[ixj]=ii; }
        }
      }
      __syncthreads();
    }
  }
  for(int i=t;i<n;i+=512){
    int idx = id[i];
    int orig = curlist ? curlist[g*n+idx] : (g*NPG0 + idx);
    if(i<k){
      perm[g*k+i]=idx; vals[g*k+i]=s[i]; nextlist[g*k+i]=orig;
    } else {
      dinvz[orig] = 0.f;               // node dies (alive sets nest)
    }
  }
}

// ---------------- gather + pool partials + next-layer degree (fused) ----------------
// Phase 1: horig[orig] = hc[perm]*vals, per-block partial mean/max into staging slot.
// Phase 2 (do_deg): recompute dinvz over the new alive set (indicator race is benign:
// alive values stay nonzero old->new, dead stay 0).
__global__ __launch_bounds__(256) void k_gpd(int n, int k, int do_deg,
    const float* __restrict__ hc, const int* __restrict__ perm, const float* __restrict__ vals,
    const int* __restrict__ nextlist, float* __restrict__ horig,
    float* __restrict__ sumst, unsigned* __restrict__ maxst,
    const int* __restrict__ rp, const long long* __restrict__ ec, float* __restrict__ dinvz){
  int g = blockIdx.x & 63;
  int chunk = blockIdx.x >> 6;
  int wid = threadIdx.x >> 6, lane = threadIdx.x & 63;
  float2 psum; psum.x = 0.f; psum.y = 0.f;
  float2 pmax; pmax.x = -FLT_MAX; pmax.y = -FLT_MAX;
  for(int j = chunk*4 + wid; j < k; j += POOL_NB*4){
    int idx = perm[g*k+j];
    float v = vals[g*k+j];
    int orig = nextlist[g*k+j];
    float2 hv = *(const float2*)(hc + (size_t)(g*n+idx)*HDIM + 2*lane);
    float2 o; o.x = hv.x*v; o.y = hv.y*v;
    *(float2*)(horig + (size_t)orig*HDIM + 2*lane) = o;
    psum.x += o.x; psum.y += o.y;
    pmax.x = fmaxf(pmax.x, o.x); pmax.y = fmaxf(pmax.y, o.y);
  }
  if(do_deg){
    for(int j = chunk*4 + wid; j < k; j += POOL_NB*4){
      int d  = nextlist[g*k + j];
      int ld = d - g*NPG0;
      int e0 = rp[g*RPS+ld], e1 = rp[g*RPS+ld+1];
      float deg = 0.f;
      for(int b=e0+lane; b<e1; b+=64){
        long long rec = ec[(size_t)g*EG + b];
        int s = (int)(rec & 0xffffffffLL);
        float w = __int_as_float((int)(rec>>32));
        if(dinvz[s] != 0.f) deg += w;
      }
      #pragma unroll
      for(int o=32;o>0;o>>=1) deg += __shfl_xor(deg, o, 64);
      if(lane==0) dinvz[d] = 1.0f / sqrtf(deg + 1.0f);
    }
  }
  __shared__ float ss[4][128];
  __shared__ float sm[4][128];
  *(float2*)&ss[wid][2*lane] = psum;
  *(float2*)&sm[wid][2*lane] = pmax;
  __syncthreads();
  int t = threadIdx.x;
  if(t < 128){
    float s = (ss[0][t]+ss[1][t]) + (ss[2][t]+ss[3][t]);
    float m = fmaxf(fmaxf(sm[0][t], sm[1][t]), fmaxf(sm[2][t], sm[3][t]));
    atomicAdd(&sumst[g*HDIM + t], s);
    atomicMax(&maxst[g*HDIM + t], ford(m));
  }
}

// ---------------- MLP head (folds the 6 per-layer staging slots) ----------------
__global__ __launch_bounds__(512) void k_head(const float* __restrict__ sumstage,
    const unsigned* __restrict__ maxstage,
    const float* __restrict__ d1w, const float* __restrict__ d1b,
    const float* __restrict__ d2w, const float* __restrict__ d2b, float* __restrict__ out){
  const float kinv[6] = {1.f/800.f, 1.f/640.f, 1.f/512.f, 1.f/410.f, 1.f/328.f, 1.f/263.f};
  int g = blockIdx.x, j = threadIdx.x;
  __shared__ float fl[256];
  __shared__ float hd[512];
  if(j < 128){
    float s = 0.f;
    #pragma unroll
    for(int l=0;l<6;l++) s += sumstage[l*NGR*HDIM + g*HDIM + j] * kinv[l];
    fl[j] = s;
  } else if(j < 256){
    int f = j - 128;
    float m = 0.f;
    #pragma unroll
    for(int l=0;l<6;l++) m += funord(maxstage[l*NGR*HDIM + g*HDIM + f]);
    fl[j] = m;
  }
  __syncthreads();
  float acc = d1b[j];
  for(int i=0;i<256;i++) acc += fl[i]*d1w[i*512+j];
  hd[j] = fmaxf(acc, 0.f);
  __syncthreads();
  if(j < 10){
    float a = d2b[j];
    for(int i=0;i<512;i++) a += hd[i]*d2w[i*10+j];
    out[g*10+j] = a;
  }
}

extern "C" void kernel_launch(void* const* d_in, const int* in_sizes, int n_in,
                              void* d_out, int out_size, void* d_ws, size_t ws_size,
                              hipStream_t stream) {
  const float* x    = (const float*)d_in[0];
  const int* ei     = (const int*)d_in[1];
  const float* ew   = (const float*)d_in[3];
  const float* conv1w = (const float*)d_in[4];
  const float* convw  = (const float*)d_in[5];
  const float* convb  = (const float*)d_in[6];
  const float* bng    = (const float*)d_in[7];
  const float* bnb    = (const float*)d_in[8];
  const float* bnm    = (const float*)d_in[9];
  const float* bnv    = (const float*)d_in[10];
  const float* poolw  = (const float*)d_in[11];
  const float* d1w    = (const float*)d_in[12];
  const float* d1b    = (const float*)d_in[13];
  const float* d2w    = (const float*)d_in[14];
  const float* d2b    = (const float*)d_in[15];
  float* out = (float*)d_out;

  char* w = (char*)d_ws;
  float* horig = (float*)w; w += (size_t)64000*128*4;   // features by original node id
  float* hc    = (float*)w; w += (size_t)64000*128*4;   // agg / gemm output (compact rows)
  float* agg0  = (float*)w; w += (size_t)64000*64*4;    // layer-0 aggregation (64 cols)
  long long* ec = (long long*)w; w += (size_t)NE*8;     // static (w, src_orig), dst-bucketed
  int*   rp    = (int*)w;   w += (size_t)NGR*RPS*4;
  int*   pcnt  = (int*)w;   w += (size_t)256*NPG0*4;
  float* pdeg  = (float*)w; w += (size_t)256*NPG0*4;
  float* dinvz = (float*)w; w += (size_t)64000*4;       // 0 == node dead
  float* score = (float*)w; w += (size_t)64000*4;
  int*   perm  = (int*)w;   w += (size_t)51200*4;
  float* vals  = (float*)w; w += (size_t)51200*4;
  int*   listA = (int*)w;   w += (size_t)51200*4;
  int*   listB = (int*)w;   w += (size_t)51200*4;
  float* invno = (float*)w; w += 64;
  float* sumstage = (float*)w; w += (size_t)6*NGR*HDIM*4;
  unsigned* maxstage = (unsigned*)w; w += (size_t)6*NGR*HDIM*4;

  k_setup<<<198,256,0,stream>>>(poolw, invno, sumstage, maxstage);

  const int ns[6]={1000,800,640,512,410,328};
  const int ks[6]={800,640,512,410,328,263};

  // ---- one-time CSR build (original ids), atomic-free count ----
  k_count0<<<256,256,0,stream>>>(ei+NE, ew, pcnt, pdeg);
  k_scan0<<<64,512,0,stream>>>(pcnt, pdeg, rp, dinvz);
  k_scatter0<<<64,1024,0,stream>>>(ei, ei+NE, ew, rp, ec);

  // ---- layer 0 (input = x, 64 cols) ----
  k_agg<1><<<64*32,256,0,stream>>>(1000, nullptr, rp, ec, dinvz, x, agg0);
  k_gemm<64><<<1000,256,0,stream>>>(agg0, conv1w, convb, bng, bnb, bnm, bnv, poolw, invno, hc, score);
  k_topk<<<64,512,0,stream>>>(1000, 800, 1024, score, nullptr, perm, vals, listA, dinvz);
  k_gpd<<<64*POOL_NB,256,0,stream>>>(1000, 800, 1, hc, perm, vals, listA, horig,
                                     sumstage, maxstage, rp, ec, dinvz);

  // ---- layers 1..5 ----
  int* cur = listA; int* nxt = listB;
  for(int i=1;i<6;i++){
    int n = ns[i], k = ks[i];
    k_agg<0><<<64*32,256,0,stream>>>(n, cur, rp, ec, dinvz, horig, hc);
    k_gemm<128><<<n,256,0,stream>>>(hc, convw+(size_t)(i-1)*128*128, convb+i*128, bng+i*128,
                                    bnb+i*128, bnm+i*128, bnv+i*128, poolw+i*128, invno+i, hc, score);
    int P = (n > 512) ? 1024 : 512;
    k_topk<<<64,512,0,stream>>>(n, k, P, score, cur, perm, vals, nxt, dinvz);
    k_gpd<<<64*POOL_NB,256,0,stream>>>(n, k, (i<5)?1:0, hc, perm, vals, nxt, horig,
                                       sumstage + i*NGR*HDIM, maxstage + i*NGR*HDIM,
                                       rp, ec, dinvz);
    int* tmp = cur; cur = nxt; nxt = tmp;
  }

  k_head<<<64,512,0,stream>>>(sumstage, maxstage, d1w, d1b, d2w, d2b, out);
}

// Round 7
// 720.147 us; speedup vs baseline: 2.5988x; 1.0652x over previous
//
#include <hip/hip_runtime.h>
#include <float.h>
#include <math.h>

#define NGR 64        // graphs
#define NPG0 1000     // original nodes per graph
#define HDIM 128
#define EG 16000      // edges per graph
#define NE (NGR*EG)   // 1,024,000
#define RPS 1008      // rp row stride
#define BNEPS 1e-5f
#define POOL_NB 8

// monotone float<->uint order mapping (no NaNs in this workload)
__device__ __forceinline__ unsigned ford(float x){
  unsigned u = __float_as_uint(x);
  return (u & 0x80000000u) ? ~u : (u | 0x80000000u);
}
__device__ __forceinline__ float funord(unsigned u){
  return (u & 0x80000000u) ? __uint_as_float(u ^ 0x80000000u) : __uint_as_float(~u);
}
#define FORD_NEGMAX 0x00800000u   // ford(-FLT_MAX)

// ---------------- setup: invnorm (blocks 0..5) + staging init (blocks 6..197) ----------------
__global__ __launch_bounds__(256) void k_setup(const float* __restrict__ pw,
    float* __restrict__ invnorm, float* __restrict__ sumstage, unsigned* __restrict__ maxstage){
  if(blockIdx.x < 6){
    int i = blockIdx.x, t = threadIdx.x;
    __shared__ float red[2];
    if(t < 128){
      float v = pw[i*HDIM + t];
      float s = v*v;
      #pragma unroll
      for(int o=32;o>0;o>>=1) s += __shfl_down(s, o, 64);
      if((t & 63)==0) red[t>>6] = s;
    }
    __syncthreads();
    if(t==0) invnorm[i] = 1.0f / sqrtf(red[0]+red[1]);
  } else {
    int i = (blockIdx.x-6)*256 + threadIdx.x;   // 6*64*128 = 49152 elements
    if(i < 6*NGR*HDIM){ sumstage[i] = 0.f; maxstage[i] = FORD_NEGMAX; }
  }
}

// ---------------- build phase: per-graph-chunk LDS count + weighted degree (atomic-free out) ----------------
__global__ __launch_bounds__(256) void k_count0(const int* __restrict__ dst,
    const float* __restrict__ we, int* __restrict__ pcnt, float* __restrict__ pdeg){
  int g = blockIdx.x >> 2, sub = blockIdx.x & 3, t = threadIdx.x;
  __shared__ int   cnt[NPG0];
  __shared__ float degl[NPG0];
  for(int i=t;i<NPG0;i+=256){ cnt[i]=0; degl[i]=0.f; }
  __syncthreads();
  int base = g*EG + sub*4000;
  for(int idx=t; idx<4000; idx+=256){
    int e = base + idx;
    int ld = dst[e] - g*NPG0;
    atomicAdd(&cnt[ld], 1);
    atomicAdd(&degl[ld], we[e]);
  }
  __syncthreads();
  int p = blockIdx.x * NPG0;
  for(int i=t;i<NPG0;i+=256){ pcnt[p+i] = cnt[i]; pdeg[p+i] = degl[i]; }
}

__global__ __launch_bounds__(512) void k_scan0(const int* __restrict__ pcnt,
    const float* __restrict__ pdeg, int* __restrict__ rp, float* __restrict__ dinvz){
  int g = blockIdx.x, t = threadIdx.x;
  __shared__ int sc[2][1024];
  for(int i=t;i<1024;i+=512){
    int c = 0;
    if(i<NPG0){
      c = pcnt[(g*4+0)*NPG0+i] + pcnt[(g*4+1)*NPG0+i]
        + pcnt[(g*4+2)*NPG0+i] + pcnt[(g*4+3)*NPG0+i];
      float dg = pdeg[(g*4+0)*NPG0+i] + pdeg[(g*4+1)*NPG0+i]
               + pdeg[(g*4+2)*NPG0+i] + pdeg[(g*4+3)*NPG0+i];
      dinvz[g*NPG0+i] = 1.0f / sqrtf(dg + 1.0f);
    }
    sc[0][i] = c;
  }
  __syncthreads();
  int buf = 0;
  for(int d=1; d<1024; d<<=1){
    for(int i=t;i<1024;i+=512){
      int v = sc[buf][i];
      if(i>=d) v += sc[buf][i-d];
      sc[buf^1][i] = v;
    }
    __syncthreads();
    buf ^= 1;
  }
  for(int i=t;i<=NPG0;i+=512) rp[g*RPS+i] = (i==0) ? 0 : sc[buf][i-1];
}

// ---------------- scatter: per-graph LDS cursor (no global atomics) ----------------
// ec record = (float w)<<32 | src_orig  (static for whole run)
__global__ __launch_bounds__(1024) void k_scatter0(const int* __restrict__ src,
    const int* __restrict__ dst, const float* __restrict__ we,
    const int* __restrict__ rp, long long* __restrict__ ec){
  int g = blockIdx.x, t = threadIdx.x;
  __shared__ int cur[NPG0];
  for(int i=t;i<NPG0;i+=1024) cur[i] = rp[g*RPS+i];
  __syncthreads();
  int base = g*EG;
  for(int idx=t; idx<EG; idx+=1024){
    int e = base + idx;
    int ld = dst[e] - g*NPG0;
    int pos = atomicAdd(&cur[ld], 1);
    ec[(size_t)base + pos] = (((long long)__float_as_int(we[e]))<<32) | (unsigned)src[e];
  }
}

// ---------------- aggregation over original-id buckets ----------------
// agg[compact dst row] = dvd * sum_e (w*dinvz[src]) * h[src] + dvd^2 * h[d]
// Record-parallel wave split: L0 (64 cols) quarter-wave x float4 = 4 rows/load-instr;
// layers>=1 (128 cols) half-wave x float4 = 2 rows/load-instr. Doubles/quadruples
// rows in flight vs column-parallel float2.
template<int L0>
__global__ __launch_bounds__(256) void k_agg(int n, const int* __restrict__ nlist,
    const int* __restrict__ rp, const long long* __restrict__ ec,
    const float* __restrict__ dinvz, const float* __restrict__ h,
    float* __restrict__ agg){
  int g = blockIdx.x & 63;            // graph-major: XCD locality
  int chunk = blockIdx.x >> 6;
  int wid = threadIdx.x >> 6, lane = threadIdx.x & 63;
  const int wpg = (gridDim.x >> 6) * 4;
  const int half = lane >> 5, sl32 = lane & 31;   // 128-col split
  const int qw   = lane >> 4, sl16 = lane & 15;   // 64-col split
  for(int j = chunk*4 + wid; j < n; j += wpg){
    int cg = g*n + j;                               // compact row
    int d  = L0 ? (g*NPG0 + j) : nlist[cg];         // original id
    int ld = d - g*NPG0;
    int e0 = rp[g*RPS+ld], e1 = rp[g*RPS+ld+1];
    float dvd = dinvz[d];
    float4 acc; acc.x=0.f; acc.y=0.f; acc.z=0.f; acc.w=0.f;
    for(int b=e0;b<e1;b+=64){
      int mm = e1-b; if(mm>64) mm=64;
      long long rec = (lane<mm) ? ec[(size_t)g*EG + b + lane] : 0;
      int   sl = (int)(rec & 0xffffffffLL);
      float cl = __int_as_float((int)(rec>>32)) * dinvz[sl];
      long long pk = (((long long)__float_as_int(cl))<<32) | (unsigned)sl;
      if(L0){
        int mr = (mm+31) & ~31;
        for(int jj=0;jj<mr;jj+=32){
          #pragma unroll
          for(int u=0;u<8;u++){
            long long p = __shfl(pk, jj + 4*u + qw, 64);
            float c = __int_as_float((int)(p>>32));
            if(c != 0.f){
              int s = (int)(p & 0xffffffffLL);
              float4 hv = *(const float4*)(h + (size_t)s*64 + 4*sl16);
              acc.x += c*hv.x; acc.y += c*hv.y; acc.z += c*hv.z; acc.w += c*hv.w;
            }
          }
        }
      } else {
        int mr = (mm+15) & ~15;
        for(int jj=0;jj<mr;jj+=16){
          #pragma unroll
          for(int u=0;u<8;u++){
            long long p = __shfl(pk, jj + 2*u + half, 64);
            float c = __int_as_float((int)(p>>32));
            if(c != 0.f){
              int s = (int)(p & 0xffffffffLL);
              float4 hv = *(const float4*)(h + (size_t)s*HDIM + 4*sl32);
              acc.x += c*hv.x; acc.y += c*hv.y; acc.z += c*hv.z; acc.w += c*hv.w;
            }
          }
        }
      }
    }
    if(L0){
      // reduce across the 4 quarter-waves (each covered a record subset)
      acc.x += __shfl_xor(acc.x, 16, 64); acc.y += __shfl_xor(acc.y, 16, 64);
      acc.z += __shfl_xor(acc.z, 16, 64); acc.w += __shfl_xor(acc.w, 16, 64);
      acc.x += __shfl_xor(acc.x, 32, 64); acc.y += __shfl_xor(acc.y, 32, 64);
      acc.z += __shfl_xor(acc.z, 32, 64); acc.w += __shfl_xor(acc.w, 32, 64);
      if(qw==0){
        float4 hs = *(const float4*)(h + (size_t)d*64 + 4*sl16);
        float4 o;
        o.x = dvd*acc.x + dvd*dvd*hs.x; o.y = dvd*acc.y + dvd*dvd*hs.y;
        o.z = dvd*acc.z + dvd*dvd*hs.z; o.w = dvd*acc.w + dvd*dvd*hs.w;
        *(float4*)(agg + (size_t)cg*64 + 4*sl16) = o;
      }
    } else {
      acc.x += __shfl_xor(acc.x, 32, 64); acc.y += __shfl_xor(acc.y, 32, 64);
      acc.z += __shfl_xor(acc.z, 32, 64); acc.w += __shfl_xor(acc.w, 32, 64);
      if(half==0){
        float4 hs = *(const float4*)(h + (size_t)d*HDIM + 4*sl32);
        float4 o;
        o.x = dvd*acc.x + dvd*dvd*hs.x; o.y = dvd*acc.y + dvd*dvd*hs.y;
        o.z = dvd*acc.z + dvd*dvd*hs.z; o.w = dvd*acc.w + dvd*dvd*hs.w;
        *(float4*)(agg + (size_t)cg*HDIM + 4*sl32) = o;
      }
    }
  }
}

// ---------------- fp32 GEMM (64 rows x 128 cols / block) + bias + BN + ReLU + score ----------------
template<int KIN>
__global__ __launch_bounds__(256) void k_gemm(const float* __restrict__ Ain,
    const float* __restrict__ Wm, const float* __restrict__ bias,
    const float* __restrict__ gamma, const float* __restrict__ beta,
    const float* __restrict__ mean, const float* __restrict__ var,
    const float* __restrict__ pw, const float* __restrict__ invn_p,
    float* __restrict__ hc, float* __restrict__ score){
  __shared__ float As[64*68];    // row-major [row][k], stride 68
  __shared__ float Bs[64*128];   // [k][col]
  int t = threadIdx.x;
  int tx = t & 31, ty = t >> 5;  // thread: rows ty*8..+7, cols tx*4..+3
  int r0 = blockIdx.x * 64;
  float acc[8][4];
  #pragma unroll
  for(int j=0;j<8;j++){
    #pragma unroll
    for(int i=0;i<4;i++) acc[j][i]=0.f;
  }
  for(int k0=0;k0<KIN;k0+=64){
    #pragma unroll
    for(int p=0;p<16;p++){             // stage A 64x64 (coalesced, conflict-free)
      int idx = p*256 + t;
      int kk = idx & 63, rr = idx >> 6;
      As[rr*68 + kk] = Ain[(size_t)(r0+rr)*KIN + k0 + kk];
    }
    #pragma unroll
    for(int p=0;p<32;p++){             // stage B 64x128
      int idx = p*256 + t;
      int kk = idx >> 7, cc = idx & 127;
      Bs[kk*128 + cc] = Wm[(size_t)(k0+kk)*128 + cc];
    }
    __syncthreads();
    #pragma unroll 4
    for(int kk=0;kk<64;kk+=2){
      float4 b0 = *(float4*)&Bs[kk*128 + tx*4];
      float4 b1 = *(float4*)&Bs[(kk+1)*128 + tx*4];
      #pragma unroll
      for(int j=0;j<8;j++){
        float2 a = *(float2*)&As[(ty*8+j)*68 + kk];
        acc[j][0] += a.x*b0.x; acc[j][1] += a.x*b0.y;
        acc[j][2] += a.x*b0.z; acc[j][3] += a.x*b0.w;
        acc[j][0] += a.y*b1.x; acc[j][1] += a.y*b1.y;
        acc[j][2] += a.y*b1.z; acc[j][3] += a.y*b1.w;
      }
    }
    __syncthreads();
  }
  // epilogue: bias + BN + ReLU, write hc, score = tanh(dot(hc,pw)*invnorm)
  float invn = invn_p[0];
  float bi[4], scv[4], bt[4], mn[4], pwv[4];
  #pragma unroll
  for(int i=0;i<4;i++){
    int c = tx*4+i;
    bi[i]  = bias[c];
    scv[i] = gamma[c] * (1.0f/sqrtf(var[c] + BNEPS));
    bt[i]  = beta[c];
    mn[i]  = mean[c];
    pwv[i] = pw[c];
  }
  #pragma unroll
  for(int j=0;j<8;j++){
    int row = r0 + ty*8 + j;
    float v0 = fmaxf((acc[j][0]+bi[0]-mn[0])*scv[0]+bt[0], 0.f);
    float v1 = fmaxf((acc[j][1]+bi[1]-mn[1])*scv[1]+bt[1], 0.f);
    float v2 = fmaxf((acc[j][2]+bi[2]-mn[2])*scv[2]+bt[2], 0.f);
    float v3 = fmaxf((acc[j][3]+bi[3]-mn[3])*scv[3]+bt[3], 0.f);
    float4 o; o.x=v0; o.y=v1; o.z=v2; o.w=v3;
    *(float4*)(hc + (size_t)row*HDIM + tx*4) = o;
    float p = v0*pwv[0]+v1*pwv[1]+v2*pwv[2]+v3*pwv[3];
    #pragma unroll
    for(int m=16;m>=1;m>>=1) p += __shfl_xor(p, m, 64);
    if(tx==0) score[row] = tanhf(p * invn);
  }
}

// ---------------- per-graph top-k: bitonic sort (score desc, idx asc) ----------------
// Also: compose orig-id node list for next layer; zero dinvz of dropped nodes.
__global__ __launch_bounds__(512) void k_topk(int n, int k, int P,
    const float* __restrict__ score, const int* __restrict__ curlist,
    int* __restrict__ perm, float* __restrict__ vals,
    int* __restrict__ nextlist, float* __restrict__ dinvz){
  int g = blockIdx.x, t = threadIdx.x;
  __shared__ float s[1024];
  __shared__ int  id[1024];
  for(int i=t;i<P;i+=512){
    s[i]  = (i<n) ? score[g*n+i] : -FLT_MAX;
    id[i] = i;
  }
  __syncthreads();
  for(int k2=2;k2<=P;k2<<=1){
    for(int j=k2>>1;j>0;j>>=1){
      for(int i=t;i<P;i+=512){
        int ixj = i ^ j;
        if(ixj > i){
          bool desc = ((i & k2) == 0);
          float si = s[i], sx = s[ixj];
          int ii = id[i], ix = id[ixj];
          bool pre = (si > sx) || (si == sx && ii < ix);  // i precedes in desc order
          if(desc ? !pre : pre){ s[i]=sx; s[ixj]=si; id[i]=ix; id[ixj]=ii; }
        }
      }
      __syncthreads();
    }
  }
  for(int i=t;i<n;i+=512){
    int idx = id[i];
    int orig = curlist ? curlist[g*n+idx] : (g*NPG0 + idx);
    if(i<k){
      perm[g*k+i]=idx; vals[g*k+i]=s[i]; nextlist[g*k+i]=orig;
    } else {
      dinvz[orig] = 0.f;               // node dies (alive sets nest)
    }
  }
}

// ---------------- gather + pool partials + next-layer degree (fused) ----------------
__global__ __launch_bounds__(256) void k_gpd(int n, int k, int do_deg,
    const float* __restrict__ hc, const int* __restrict__ perm, const float* __restrict__ vals,
    const int* __restrict__ nextlist, float* __restrict__ horig,
    float* __restrict__ sumst, unsigned* __restrict__ maxst,
    const int* __restrict__ rp, const long long* __restrict__ ec, float* __restrict__ dinvz){
  int g = blockIdx.x & 63;
  int chunk = blockIdx.x >> 6;
  int wid = threadIdx.x >> 6, lane = threadIdx.x & 63;
  float2 psum; psum.x = 0.f; psum.y = 0.f;
  float2 pmax; pmax.x = -FLT_MAX; pmax.y = -FLT_MAX;
  for(int j = chunk*4 + wid; j < k; j += POOL_NB*4){
    int idx = perm[g*k+j];
    float v = vals[g*k+j];
    int orig = nextlist[g*k+j];
    float2 hv = *(const float2*)(hc + (size_t)(g*n+idx)*HDIM + 2*lane);
    float2 o; o.x = hv.x*v; o.y = hv.y*v;
    *(float2*)(horig + (size_t)orig*HDIM + 2*lane) = o;
    psum.x += o.x; psum.y += o.y;
    pmax.x = fmaxf(pmax.x, o.x); pmax.y = fmaxf(pmax.y, o.y);
  }
  if(do_deg){
    for(int j = chunk*4 + wid; j < k; j += POOL_NB*4){
      int d  = nextlist[g*k + j];
      int ld = d - g*NPG0;
      int e0 = rp[g*RPS+ld], e1 = rp[g*RPS+ld+1];
      float deg = 0.f;
      for(int b=e0+lane; b<e1; b+=64){
        long long rec = ec[(size_t)g*EG + b];
        int s = (int)(rec & 0xffffffffLL);
        float w = __int_as_float((int)(rec>>32));
        if(dinvz[s] != 0.f) deg += w;
      }
      #pragma unroll
      for(int o=32;o>0;o>>=1) deg += __shfl_xor(deg, o, 64);
      if(lane==0) dinvz[d] = 1.0f / sqrtf(deg + 1.0f);
    }
  }
  __shared__ float ss[4][128];
  __shared__ float sm[4][128];
  *(float2*)&ss[wid][2*lane] = psum;
  *(float2*)&sm[wid][2*lane] = pmax;
  __syncthreads();
  int t = threadIdx.x;
  if(t < 128){
    float s = (ss[0][t]+ss[1][t]) + (ss[2][t]+ss[3][t]);
    float m = fmaxf(fmaxf(sm[0][t], sm[1][t]), fmaxf(sm[2][t], sm[3][t]));
    atomicAdd(&sumst[g*HDIM + t], s);
    atomicMax(&maxst[g*HDIM + t], ford(m));
  }
}

// ---------------- MLP head (folds the 6 per-layer staging slots) ----------------
__global__ __launch_bounds__(512) void k_head(const float* __restrict__ sumstage,
    const unsigned* __restrict__ maxstage,
    const float* __restrict__ d1w, const float* __restrict__ d1b,
    const float* __restrict__ d2w, const float* __restrict__ d2b, float* __restrict__ out){
  const float kinv[6] = {1.f/800.f, 1.f/640.f, 1.f/512.f, 1.f/410.f, 1.f/328.f, 1.f/263.f};
  int g = blockIdx.x, j = threadIdx.x;
  __shared__ float fl[256];
  __shared__ float hd[512];
  if(j < 128){
    float s = 0.f;
    #pragma unroll
    for(int l=0;l<6;l++) s += sumstage[l*NGR*HDIM + g*HDIM + j] * kinv[l];
    fl[j] = s;
  } else if(j < 256){
    int f = j - 128;
    float m = 0.f;
    #pragma unroll
    for(int l=0;l<6;l++) m += funord(maxstage[l*NGR*HDIM + g*HDIM + f]);
    fl[j] = m;
  }
  __syncthreads();
  float acc = d1b[j];
  for(int i=0;i<256;i++) acc += fl[i]*d1w[i*512+j];
  hd[j] = fmaxf(acc, 0.f);
  __syncthreads();
  if(j < 10){
    float a = d2b[j];
    for(int i=0;i<512;i++) a += hd[i]*d2w[i*10+j];
    out[g*10+j] = a;
  }
}

extern "C" void kernel_launch(void* const* d_in, const int* in_sizes, int n_in,
                              void* d_out, int out_size, void* d_ws, size_t ws_size,
                              hipStream_t stream) {
  const float* x    = (const float*)d_in[0];
  const int* ei     = (const int*)d_in[1];
  const float* ew   = (const float*)d_in[3];
  const float* conv1w = (const float*)d_in[4];
  const float* convw  = (const float*)d_in[5];
  const float* convb  = (const float*)d_in[6];
  const float* bng    = (const float*)d_in[7];
  const float* bnb    = (const float*)d_in[8];
  const float* bnm    = (const float*)d_in[9];
  const float* bnv    = (const float*)d_in[10];
  const float* poolw  = (const float*)d_in[11];
  const float* d1w    = (const float*)d_in[12];
  const float* d1b    = (const float*)d_in[13];
  const float* d2w    = (const float*)d_in[14];
  const float* d2b    = (const float*)d_in[15];
  float* out = (float*)d_out;

  char* w = (char*)d_ws;
  float* horig = (float*)w; w += (size_t)64000*128*4;   // features by original node id
  float* hc    = (float*)w; w += (size_t)64000*128*4;   // agg / gemm output (compact rows)
  float* agg0  = (float*)w; w += (size_t)64000*64*4;    // layer-0 aggregation (64 cols)
  long long* ec = (long long*)w; w += (size_t)NE*8;     // static (w, src_orig), dst-bucketed
  int*   rp    = (int*)w;   w += (size_t)NGR*RPS*4;
  int*   pcnt  = (int*)w;   w += (size_t)256*NPG0*4;
  float* pdeg  = (float*)w; w += (size_t)256*NPG0*4;
  float* dinvz = (float*)w; w += (size_t)64000*4;       // 0 == node dead
  float* score = (float*)w; w += (size_t)64000*4;
  int*   perm  = (int*)w;   w += (size_t)51200*4;
  float* vals  = (float*)w; w += (size_t)51200*4;
  int*   listA = (int*)w;   w += (size_t)51200*4;
  int*   listB = (int*)w;   w += (size_t)51200*4;
  float* invno = (float*)w; w += 64;
  float* sumstage = (float*)w; w += (size_t)6*NGR*HDIM*4;
  unsigned* maxstage = (unsigned*)w; w += (size_t)6*NGR*HDIM*4;

  k_setup<<<198,256,0,stream>>>(poolw, invno, sumstage, maxstage);

  const int ns[6]={1000,800,640,512,410,328};
  const int ks[6]={800,640,512,410,328,263};

  // ---- one-time CSR build (original ids), atomic-free count ----
  k_count0<<<256,256,0,stream>>>(ei+NE, ew, pcnt, pdeg);
  k_scan0<<<64,512,0,stream>>>(pcnt, pdeg, rp, dinvz);
  k_scatter0<<<64,1024,0,stream>>>(ei, ei+NE, ew, rp, ec);

  // ---- layer 0 (input = x, 64 cols) ----
  k_agg<1><<<64*32,256,0,stream>>>(1000, nullptr, rp, ec, dinvz, x, agg0);
  k_gemm<64><<<1000,256,0,stream>>>(agg0, conv1w, convb, bng, bnb, bnm, bnv, poolw, invno, hc, score);
  k_topk<<<64,512,0,stream>>>(1000, 800, 1024, score, nullptr, perm, vals, listA, dinvz);
  k_gpd<<<64*POOL_NB,256,0,stream>>>(1000, 800, 1, hc, perm, vals, listA, horig,
                                     sumstage, maxstage, rp, ec, dinvz);

  // ---- layers 1..5 ----
  int* cur = listA; int* nxt = listB;
  for(int i=1;i<6;i++){
    int n = ns[i], k = ks[i];
    k_agg<0><<<64*32,256,0,stream>>>(n, cur, rp, ec, dinvz, horig, hc);
    k_gemm<128><<<n,256,0,stream>>>(hc, convw+(size_t)(i-1)*128*128, convb+i*128, bng+i*128,
                                    bnb+i*128, bnm+i*128, bnv+i*128, poolw+i*128, invno+i, hc, score);
    int P = (n > 512) ? 1024 : 512;
    k_topk<<<64,512,0,stream>>>(n, k, P, score, cur, perm, vals, nxt, dinvz);
    k_gpd<<<64*POOL_NB,256,0,stream>>>(n, k, (i<5)?1:0, hc, perm, vals, nxt, horig,
                                       sumstage + i*NGR*HDIM, maxstage + i*NGR*HDIM,
                                       rp, ec, dinvz);
    int* tmp = cur; cur = nxt; nxt = tmp;
  }

  k_head<<<64,512,0,stream>>>(sumstage, maxstage, d1w, d1b, d2w, d2b, out);
}